// Round 2
// baseline (821.120 us; speedup 1.0000x reference)
//
#include <hip/hip_runtime.h>

#define N_NODE 50000
#define NEDGE  600000
#define SCAN_BLOCKS 196   // ceil(50000/256)

// ---------------- CSR build via linked lists ----------------
// rel 0 = dd (dst=drug), 1 = gd (dst=drug), 2 = dg (dst=gene), 3 = gg (dst=gene)

// One pass: count degrees AND build per-dst LIFO linked lists.
// Only stores are next[e] (coalesced); atomics hit 1.6 MB of L2-resident ints.
__global__ __launch_bounds__(256) void k_fuse(
    const int* __restrict__ d0, const int* __restrict__ d1,
    const int* __restrict__ d2, const int* __restrict__ d3,
    int* __restrict__ cnt, int* __restrict__ head, int* __restrict__ next)
{
    int idx = blockIdx.x * 256 + threadIdx.x;
    if (idx >= 4 * NEDGE) return;
    int rel = idx / NEDGE;
    int e   = idx - rel * NEDGE;
    const int* dp = rel == 0 ? d0 : rel == 1 ? d1 : rel == 2 ? d2 : d3;
    int dst = dp[e];
    atomicAdd(&cnt[rel * N_NODE + dst], 1);
    int old = atomicExch(&head[rel * N_NODE + dst], e);
    next[idx] = old;
}

__global__ __launch_bounds__(256) void k_scanA(
    const int* __restrict__ cnt, int* __restrict__ off, int* __restrict__ bsum)
{
    int rel = blockIdx.x / SCAN_BLOCKS;
    int b   = blockIdx.x - rel * SCAN_BLOCKS;
    int i   = b * 256 + threadIdx.x;
    int v   = (i < N_NODE) ? cnt[rel * N_NODE + i] : 0;
    __shared__ int sh[256];
    sh[threadIdx.x] = v;
    __syncthreads();
    for (int d = 1; d < 256; d <<= 1) {
        int t = (threadIdx.x >= d) ? sh[threadIdx.x - d] : 0;
        __syncthreads();
        sh[threadIdx.x] += t;
        __syncthreads();
    }
    if (i < N_NODE) off[rel * (N_NODE + 1) + i] = sh[threadIdx.x] - v;  // block-local exclusive
    if (threadIdx.x == 255) bsum[rel * 200 + b] = sh[255];
}

__global__ __launch_bounds__(256) void k_scanB(int* __restrict__ bsum)
{
    int rel = blockIdx.x;
    int tid = threadIdx.x;
    int v = (tid < SCAN_BLOCKS) ? bsum[rel * 200 + tid] : 0;
    __shared__ int sh[256];
    sh[tid] = v;
    __syncthreads();
    for (int d = 1; d < 256; d <<= 1) {
        int t = (tid >= d) ? sh[tid - d] : 0;
        __syncthreads();
        sh[tid] += t;
        __syncthreads();
    }
    if (tid < SCAN_BLOCKS) bsum[rel * 200 + tid] = sh[tid] - v;  // exclusive over block sums
}

__global__ __launch_bounds__(256) void k_scanC(
    int* __restrict__ off, const int* __restrict__ bsum)
{
    int rel = blockIdx.x / SCAN_BLOCKS;
    int b   = blockIdx.x - rel * SCAN_BLOCKS;
    int i   = b * 256 + threadIdx.x;
    if (i < N_NODE) {
        off[rel * (N_NODE + 1) + i] += bsum[rel * 200 + b];
    }
    if (b == 0 && threadIdx.x == 0) off[rel * (N_NODE + 1) + N_NODE] = NEDGE;
}

// One thread per (rel,node): walk the LIFO list, write src ids contiguously
// at off[node]. Consecutive threads write consecutive ranges -> ~1x write amp.
__global__ __launch_bounds__(256) void k_order(
    const int* __restrict__ s0, const int* __restrict__ s1,
    const int* __restrict__ s2, const int* __restrict__ s3,
    const int* __restrict__ head, const int* __restrict__ next,
    const int* __restrict__ off, int* __restrict__ edges)
{
    int tid = blockIdx.x * 256 + threadIdx.x;
    if (tid >= 4 * N_NODE) return;
    int rel = tid / N_NODE;
    int n   = tid - rel * N_NODE;
    const int* sp = rel == 0 ? s0 : rel == 1 ? s1 : rel == 2 ? s2 : s3;
    const int* nx = next + rel * NEDGE;
    int pos = rel * NEDGE + off[rel * (N_NODE + 1) + n];
    int e = head[tid];
    while (e >= 0) {
        edges[pos++] = sp[e];
        e = nx[e];
    }
}

// ---------------- fused dual-weight GEMM: out = X @ [Wa | Wb] ----------------
template <int K, int NOUT>
__global__ __launch_bounds__(256) void k_gemm_dual(
    const float* __restrict__ X, const float* __restrict__ Wa,
    const float* __restrict__ Wb, float* __restrict__ out, int M)
{
    constexpr int N    = NOUT / 2;
    constexpr int TXC  = NOUT / 4;   // thread-columns (4 cols each)
    constexpr int TYC  = 256 / TXC;  // row groups
    constexpr int ROWS = TYC * 4;    // rows per block
    __shared__ float Wc[K * NOUT];
    for (int i = threadIdx.x; i < K * NOUT; i += 256) {
        int k = i / NOUT, c = i - k * NOUT;
        Wc[i] = (c < N) ? Wa[k * N + c] : Wb[k * N + (c - N)];
    }
    __syncthreads();

    int tx = threadIdx.x % TXC, ty = threadIdx.x / TXC;
    int row0 = blockIdx.x * ROWS + ty * 4;
    int c0   = tx * 4;

    float acc[4][4] = {};
    const float* xr[4];
    bool rv[4];
#pragma unroll
    for (int i = 0; i < 4; i++) {
        int r = row0 + i;
        rv[i] = (r < M);
        xr[i] = X + (size_t)(rv[i] ? r : (M - 1)) * K;
    }

    for (int k = 0; k < K; k += 4) {
        float4 xv[4];
#pragma unroll
        for (int i = 0; i < 4; i++) xv[i] = *(const float4*)(xr[i] + k);
#pragma unroll
        for (int kk = 0; kk < 4; kk++) {
            float4 w = *(const float4*)&Wc[(k + kk) * NOUT + c0];
#pragma unroll
            for (int i = 0; i < 4; i++) {
                float xs = ((const float*)&xv[i])[kk];
                acc[i][0] += xs * w.x;
                acc[i][1] += xs * w.y;
                acc[i][2] += xs * w.z;
                acc[i][3] += xs * w.w;
            }
        }
    }
#pragma unroll
    for (int i = 0; i < 4; i++) {
        if (rv[i]) {
            *(float4*)(out + (size_t)(row0 + i) * NOUT + c0) =
                make_float4(acc[i][0], acc[i][1], acc[i][2], acc[i][3]);
        }
    }
}

// ---------------- segment-mean gathers ----------------
__device__ __forceinline__ float seg_sum64(
    const float* __restrict__ m, int ldm, int col,
    const int* __restrict__ off, const int* __restrict__ edges,
    int node, int lane, int* deg_out)
{
    int beg = off[node], end = off[node + 1];
    *deg_out = end - beg;
    float s = 0.f, s2 = 0.f;
    for (int e = beg; e < end; e += 64) {
        int nb = min(64, end - e);
        int eidx = (lane < nb) ? edges[e + lane] : 0;
        int j = 0;
        for (; j + 1 < nb; j += 2) {
            int sa = __shfl(eidx, j);
            int sb = __shfl(eidx, j + 1);
            s  += m[(size_t)sa * ldm + col + lane];
            s2 += m[(size_t)sb * ldm + col + lane];
        }
        if (j < nb) {
            int sa = __shfl(eidx, j);
            s += m[(size_t)sa * ldm + col + lane];
        }
    }
    return s + s2;
}

__global__ __launch_bounds__(256) void k_gather64(
    const float* __restrict__ mA, int colA, const float* __restrict__ mB, int colB,
    const int* __restrict__ offA, const int* __restrict__ eA,
    const int* __restrict__ offB, const int* __restrict__ eB,
    const float* __restrict__ bias, float* __restrict__ out, int ldm, int relu)
{
    int wid  = (blockIdx.x * 256 + threadIdx.x) >> 6;
    int lane = threadIdx.x & 63;
    if (wid >= N_NODE) return;
    int degA, degB;
    float sA = seg_sum64(mA, ldm, colA, offA, eA, wid, lane, &degA);
    float sB = seg_sum64(mB, ldm, colB, offB, eB, wid, lane, &degB);
    float h = sA / (float)max(degA, 1) + sB / (float)max(degB, 1) + bias[lane];
    if (relu) h = fmaxf(h, 0.f);
    out[(size_t)wid * 64 + lane] = h;
}

__device__ __forceinline__ float seg_sum32(
    const float* __restrict__ m, int ldm, int col,
    const int* __restrict__ off, const int* __restrict__ edges,
    int node, int lane, int* deg_out)
{
    int f = lane & 31, half = lane >> 5;
    int beg = off[node], end = off[node + 1];
    *deg_out = end - beg;
    float s = 0.f;
    for (int e = beg; e < end; e += 64) {
        int nb = min(64, end - e);
        int eidx = (lane < nb) ? edges[e + lane] : 0;
        for (int j = half; j < nb; j += 2) {
            int sa = __shfl(eidx, j);
            s += m[(size_t)sa * ldm + col + f];
        }
    }
    s += __shfl_xor(s, 32);
    return s;
}

__global__ __launch_bounds__(256) void k_gather32(
    const float* __restrict__ mA, int colA, const float* __restrict__ mB, int colB,
    const int* __restrict__ offA, const int* __restrict__ eA,
    const int* __restrict__ offB, const int* __restrict__ eB,
    const float* __restrict__ bias, float* __restrict__ out, int ldm)
{
    int wid  = (blockIdx.x * 256 + threadIdx.x) >> 6;
    int lane = threadIdx.x & 63;
    if (wid >= N_NODE) return;
    int f = lane & 31;
    int degA, degB;
    float sA = seg_sum32(mA, ldm, colA, offA, eA, wid, lane, &degA);
    float sB = seg_sum32(mB, ldm, colB, offB, eB, wid, lane, &degB);
    float h = sA / (float)max(degA, 1) + sB / (float)max(degB, 1) + bias[f];
    if (lane < 32) out[(size_t)wid * 32 + f] = h;
}

// ---------------- launcher ----------------
extern "C" void kernel_launch(void* const* d_in, const int* in_sizes, int n_in,
                              void* d_out, int out_size, void* d_ws, size_t ws_size,
                              hipStream_t stream)
{
    const float* xd = (const float*)d_in[0];
    const float* xg = (const float*)d_in[1];
    const int* dd_src = (const int*)d_in[2];  const int* dd_dst = (const int*)d_in[3];
    const int* dg_src = (const int*)d_in[4];  const int* dg_dst = (const int*)d_in[5];
    const int* gd_src = (const int*)d_in[6];  const int* gd_dst = (const int*)d_in[7];
    const int* gg_src = (const int*)d_in[8];  const int* gg_dst = (const int*)d_in[9];
    const float* W1dd = (const float*)d_in[10];
    const float* W1dg = (const float*)d_in[11];
    const float* W1gd = (const float*)d_in[12];
    const float* W1gg = (const float*)d_in[13];
    const float* b1d  = (const float*)d_in[14];
    const float* b1g  = (const float*)d_in[15];
    const float* W2dd = (const float*)d_in[16];
    const float* W2dg = (const float*)d_in[17];
    const float* W2gd = (const float*)d_in[18];
    const float* W2gg = (const float*)d_in[19];
    const float* b2d  = (const float*)d_in[20];
    const float* b2g  = (const float*)d_in[21];
    float* out = (float*)d_out;

    // workspace layout (~89 MB, same footprint as R1)
    int* cnt    = (int*)d_ws;                 // 4*50000
    int* off    = cnt + 4 * N_NODE;           // 4*(50000+1)
    int* bsum   = off + 4 * (N_NODE + 1);     // 4*200
    int* edges  = bsum + 4 * 200;             // 4*600000
    float* md1  = (float*)(edges + 4 * NEDGE);        // 50000*128
    float* mg1  = md1 + (size_t)N_NODE * 128;         // 50000*128
    float* hd   = mg1 + (size_t)N_NODE * 128;         // 50000*64
    float* hg   = hd + (size_t)N_NODE * 64;           // 50000*64
    float* md2  = md1;  // layer-1 m dead after gather64 -> reuse
    float* mg2  = mg1;
    // CSR-build temporaries overlay md1/mg1 (dead until the GEMMs run):
    int* next = (int*)md1;   // 4*NEDGE ints (9.6 MB) < 25.6 MB region
    int* head = (int*)mg1;   // 4*N_NODE ints

    // ---- CSR build (shared by both layers) ----
    hipMemsetAsync(cnt, 0, 4 * N_NODE * sizeof(int), stream);
    hipMemsetAsync(head, 0xFF, 4 * N_NODE * sizeof(int), stream);  // head = -1
    k_fuse<<<(4 * NEDGE + 255) / 256, 256, 0, stream>>>(
        dd_dst, gd_dst, dg_dst, gg_dst, cnt, head, next);
    k_scanA<<<4 * SCAN_BLOCKS, 256, 0, stream>>>(cnt, off, bsum);
    k_scanB<<<4, 256, 0, stream>>>(bsum);
    k_scanC<<<4 * SCAN_BLOCKS, 256, 0, stream>>>(off, bsum);
    k_order<<<(4 * N_NODE + 255) / 256, 256, 0, stream>>>(
        dd_src, gd_src, dg_src, gg_src, head, next, off, edges);

    const int* off_dd = off + 0 * (N_NODE + 1);
    const int* off_gd = off + 1 * (N_NODE + 1);
    const int* off_dg = off + 2 * (N_NODE + 1);
    const int* off_gg = off + 3 * (N_NODE + 1);
    const int* e_dd = edges + 0 * NEDGE;
    const int* e_gd = edges + 1 * NEDGE;
    const int* e_dg = edges + 2 * NEDGE;
    const int* e_gg = edges + 3 * NEDGE;

    // ---- layer 1: md1 = xd @ [W1dd|W1dg], mg1 = xg @ [W1gd|W1gg] ----
    k_gemm_dual<128, 128><<<(N_NODE + 31) / 32, 256, 0, stream>>>(xd, W1dd, W1dg, md1, N_NODE);
    k_gemm_dual<128, 128><<<(N_NODE + 31) / 32, 256, 0, stream>>>(xg, W1gd, W1gg, mg1, N_NODE);
    // hd = mean_dd(md1[:, :64]) + mean_gd(mg1[:, :64]) + b1d, relu
    k_gather64<<<(N_NODE * 64) / 256, 256, 0, stream>>>(
        md1, 0, mg1, 0, off_dd, e_dd, off_gd, e_gd, b1d, hd, 128, 1);
    // hg = mean_dg(md1[:, 64:]) + mean_gg(mg1[:, 64:]) + b1g, relu
    k_gather64<<<(N_NODE * 64) / 256, 256, 0, stream>>>(
        md1, 64, mg1, 64, off_dg, e_dg, off_gg, e_gg, b1g, hg, 128, 1);

    // ---- layer 2: md2 = hd @ [W2dd|W2dg], mg2 = hg @ [W2gd|W2gg] ----
    k_gemm_dual<64, 64><<<(N_NODE + 63) / 64, 256, 0, stream>>>(hd, W2dd, W2dg, md2, N_NODE);
    k_gemm_dual<64, 64><<<(N_NODE + 63) / 64, 256, 0, stream>>>(hg, W2gd, W2gg, mg2, N_NODE);
    // out rows [0, N_DRUG): drug embeddings
    k_gather32<<<(N_NODE * 64) / 256, 256, 0, stream>>>(
        md2, 0, mg2, 0, off_dd, e_dd, off_gd, e_gd, b2d, out, 64);
    // out rows [N_DRUG, N_DRUG+N_GENE): gene embeddings
    k_gather32<<<(N_NODE * 64) / 256, 256, 0, stream>>>(
        md2, 32, mg2, 32, off_dg, e_dg, off_gg, e_gg, b2g, out + (size_t)N_NODE * 32, 64);
}

// Round 3
// 609.247 us; speedup vs baseline: 1.3478x; 1.3478x over previous
//
#include <hip/hip_runtime.h>

#define N_NODE 50000
#define NEDGE  600000
#define NRANGE 32
#define RSZ    1563      // ceil(N_NODE / NRANGE); 32*1563 = 50016 >= 50000
#define CAP    24576     // per-range staging capacity (avg 18750, sigma~135)
#define CHUNK  8192
#define NBLK1  74        // ceil(NEDGE / CHUNK)

// rel 0 = dd (dst=drug), 1 = gd (dst=drug), 2 = dg (dst=gene), 3 = gg (dst=gene)

// ---------- stage A: per-block range histograms (no global atomics) ----------
__global__ __launch_bounds__(256) void k_rangecount(
    const int* __restrict__ d0, const int* __restrict__ d1,
    const int* __restrict__ d2, const int* __restrict__ d3,
    int* __restrict__ part)
{
    __shared__ int h[4 * NRANGE];
    int tid = threadIdx.x;
    if (tid < 128) h[tid] = 0;
    __syncthreads();
    int stride = gridDim.x * 256;
    int gid = blockIdx.x * 256 + tid;
#pragma unroll
    for (int rel = 0; rel < 4; rel++) {
        const int* dp = rel == 0 ? d0 : rel == 1 ? d1 : rel == 2 ? d2 : d3;
        for (int e = gid; e < NEDGE; e += stride)
            atomicAdd(&h[rel * NRANGE + dp[e] / RSZ], 1);
    }
    __syncthreads();
    if (tid < 128) part[blockIdx.x * 128 + tid] = h[tid];
}

// ---------- stage B: reduce partials, scan to range bases ----------
__global__ __launch_bounds__(128) void k_rangebase(
    const int* __restrict__ part, int* __restrict__ base_g, int* __restrict__ gcur)
{
    __shared__ int tot[128];
    int t = threadIdx.x;
    int s = 0;
    for (int b = 0; b < 256; b++) s += part[b * 128 + t];
    tot[t] = s;
    __syncthreads();
    if (t == 0) {
        int run = 0;
        for (int i = 0; i < 128; i++) {
            int x = tot[i];
            base_g[i] = run;
            gcur[i]   = run;
            run += x;
        }
        base_g[128] = run;   // sentinel = 4*NEDGE
    }
}

// ---------- stage C: partition edges into (rel,range) buckets, LDS-staged ----------
__global__ __launch_bounds__(256) void k_part(
    const int* __restrict__ d0, const int* __restrict__ s0,
    const int* __restrict__ d1, const int* __restrict__ s1,
    const int* __restrict__ d2, const int* __restrict__ s2,
    const int* __restrict__ d3, const int* __restrict__ s3,
    int* __restrict__ gcur, unsigned* __restrict__ gpart)
{
    __shared__ int hcur[NRANGE];      // hist -> cursor (chunk-local offsets)
    __shared__ int gbase[NRANGE];     // reserved global base per bucket
    __shared__ unsigned buf[CHUNK];   // packed (dst_local<<16)|src
    int bid = blockIdx.x;
    int rel = bid / NBLK1;
    int c   = bid - rel * NBLK1;
    int tid = threadIdx.x;
    const int* dp = rel == 0 ? d0 : rel == 1 ? d1 : rel == 2 ? d2 : d3;
    const int* sp = rel == 0 ? s0 : rel == 1 ? s1 : rel == 2 ? s2 : s3;
    int e0 = c * CHUNK;
    int e1 = min(e0 + CHUNK, NEDGE);
    int cnt_chunk = e1 - e0;

    if (tid < NRANGE) hcur[tid] = 0;
    __syncthreads();
    for (int e = e0 + tid; e < e1; e += 256)
        atomicAdd(&hcur[dp[e] / RSZ], 1);
    __syncthreads();
    int mycnt = (tid < NRANGE) ? hcur[tid] : 0;
    __syncthreads();
    if (tid == 0) {
        int run = 0;
        for (int i = 0; i < NRANGE; i++) { int x = hcur[i]; hcur[i] = run; run += x; }
    }
    __syncthreads();
    if (tid < NRANGE) gbase[tid] = atomicAdd(&gcur[rel * NRANGE + tid], mycnt);
    __syncthreads();
    // bin packed pairs into LDS at chunk-local positions
    for (int e = e0 + tid; e < e1; e += 256) {
        int d = dp[e];
        int u = d / RSZ;
        int p = atomicAdd(&hcur[u], 1);
        buf[p] = ((unsigned)(d - u * RSZ) << 16) | (unsigned)sp[e];
    }
    __syncthreads();
    // hcur[u] is now the inclusive end of bucket u; write runs coalesced
    for (int i = tid; i < cnt_chunk; i += 256) {
        int lo = 0, hi = NRANGE - 1;
        while (lo < hi) { int mid = (lo + hi) >> 1; if (hcur[mid] > i) hi = mid; else lo = mid + 1; }
        int beg = (lo == 0) ? 0 : hcur[lo - 1];
        gpart[gbase[lo] + (i - beg)] = buf[i];
    }
}

// ---------- stage D: per (rel,range) block -> final CSR (off + edges) ----------
__global__ __launch_bounds__(256) void k_csr(
    const unsigned* __restrict__ gpart, const int* __restrict__ base_g,
    int* __restrict__ off, int* __restrict__ edges)
{
    __shared__ int cur[RSZ];
    __shared__ unsigned short stg[CAP];
    __shared__ int sc[256];
    int bid = blockIdx.x;
    int rel = bid >> 5, r = bid & 31;
    int tid = threadIdx.x;
    int range0 = r * RSZ;
    int RS = min(RSZ, N_NODE - range0);
    int base_abs = base_g[bid];
    int count    = base_g[bid + 1] - base_abs;
    int base_rel = base_abs - rel * NEDGE;

    for (int i = tid; i < RSZ; i += 256) cur[i] = 0;
    __syncthreads();
    for (int i = tid; i < count; i += 256)
        atomicAdd(&cur[gpart[base_abs + i] >> 16], 1);
    __syncthreads();
    // block scan of cur[0..RSZ)
    int vloc[7]; int run = 0;
#pragma unroll
    for (int j = 0; j < 7; j++) {
        int idx = tid * 7 + j;
        int x = (idx < RSZ) ? cur[idx] : 0;
        vloc[j] = x; run += x;
    }
    sc[tid] = run;
    __syncthreads();
    for (int d = 1; d < 256; d <<= 1) {
        int t = (tid >= d) ? sc[tid - d] : 0;
        __syncthreads();
        sc[tid] += t;
        __syncthreads();
    }
    int excl = sc[tid] - run;
    run = excl;
#pragma unroll
    for (int j = 0; j < 7; j++) {
        int idx = tid * 7 + j;
        if (idx < RSZ) { int x = vloc[j]; cur[idx] = run; run += x; }
    }
    __syncthreads();
    // write off for this range (cur holds exclusive offsets)
    for (int i = tid; i < RS; i += 256)
        off[rel * (N_NODE + 1) + range0 + i] = base_rel + cur[i];
    if (r == NRANGE - 1 && tid == 0) off[rel * (N_NODE + 1) + N_NODE] = NEDGE;
    __syncthreads();
    if (count <= CAP) {
        for (int i = tid; i < count; i += 256) {
            unsigned v = gpart[base_abs + i];
            int p = atomicAdd(&cur[v >> 16], 1);
            stg[p] = (unsigned short)(v & 0xFFFFu);
        }
        __syncthreads();
        for (int i = tid; i < count; i += 256)
            edges[base_abs + i] = (int)stg[i];
    } else {
        // fallback (statistically unreachable): direct scatter, correct but slow
        for (int i = tid; i < count; i += 256) {
            unsigned v = gpart[base_abs + i];
            int p = atomicAdd(&cur[v >> 16], 1);
            edges[base_abs + p] = (int)(v & 0xFFFFu);
        }
    }
}

// ---------------- fused dual-weight GEMM: out = X @ [Wa | Wb] ----------------
template <int K, int NOUT>
__global__ __launch_bounds__(256) void k_gemm_dual(
    const float* __restrict__ X, const float* __restrict__ Wa,
    const float* __restrict__ Wb, float* __restrict__ out, int M)
{
    constexpr int N    = NOUT / 2;
    constexpr int TXC  = NOUT / 4;
    constexpr int TYC  = 256 / TXC;
    constexpr int ROWS = TYC * 4;
    __shared__ float Wc[K * NOUT];
    for (int i = threadIdx.x; i < K * NOUT; i += 256) {
        int k = i / NOUT, c = i - k * NOUT;
        Wc[i] = (c < N) ? Wa[k * N + c] : Wb[k * N + (c - N)];
    }
    __syncthreads();

    int tx = threadIdx.x % TXC, ty = threadIdx.x / TXC;
    int row0 = blockIdx.x * ROWS + ty * 4;
    int c0   = tx * 4;

    float acc[4][4] = {};
    const float* xr[4];
    bool rv[4];
#pragma unroll
    for (int i = 0; i < 4; i++) {
        int r = row0 + i;
        rv[i] = (r < M);
        xr[i] = X + (size_t)(rv[i] ? r : (M - 1)) * K;
    }

    for (int k = 0; k < K; k += 4) {
        float4 xv[4];
#pragma unroll
        for (int i = 0; i < 4; i++) xv[i] = *(const float4*)(xr[i] + k);
#pragma unroll
        for (int kk = 0; kk < 4; kk++) {
            float4 w = *(const float4*)&Wc[(k + kk) * NOUT + c0];
#pragma unroll
            for (int i = 0; i < 4; i++) {
                float xs = ((const float*)&xv[i])[kk];
                acc[i][0] += xs * w.x;
                acc[i][1] += xs * w.y;
                acc[i][2] += xs * w.z;
                acc[i][3] += xs * w.w;
            }
        }
    }
#pragma unroll
    for (int i = 0; i < 4; i++) {
        if (rv[i]) {
            *(float4*)(out + (size_t)(row0 + i) * NOUT + c0) =
                make_float4(acc[i][0], acc[i][1], acc[i][2], acc[i][3]);
        }
    }
}

// ---------------- segment-mean gathers ----------------
__device__ __forceinline__ float seg_sum64(
    const float* __restrict__ m, int ldm, int col,
    const int* __restrict__ off, const int* __restrict__ edges,
    int node, int lane, int* deg_out)
{
    int beg = off[node], end = off[node + 1];
    *deg_out = end - beg;
    float s = 0.f, s2 = 0.f;
    for (int e = beg; e < end; e += 64) {
        int nb = min(64, end - e);
        int eidx = (lane < nb) ? edges[e + lane] : 0;
        int j = 0;
        for (; j + 1 < nb; j += 2) {
            int sa = __shfl(eidx, j);
            int sb = __shfl(eidx, j + 1);
            s  += m[(size_t)sa * ldm + col + lane];
            s2 += m[(size_t)sb * ldm + col + lane];
        }
        if (j < nb) {
            int sa = __shfl(eidx, j);
            s += m[(size_t)sa * ldm + col + lane];
        }
    }
    return s + s2;
}

__global__ __launch_bounds__(256) void k_gather64(
    const float* __restrict__ mA, int colA, const float* __restrict__ mB, int colB,
    const int* __restrict__ offA, const int* __restrict__ eA,
    const int* __restrict__ offB, const int* __restrict__ eB,
    const float* __restrict__ bias, float* __restrict__ out, int ldm, int relu)
{
    int wid  = (blockIdx.x * 256 + threadIdx.x) >> 6;
    int lane = threadIdx.x & 63;
    if (wid >= N_NODE) return;
    int degA, degB;
    float sA = seg_sum64(mA, ldm, colA, offA, eA, wid, lane, &degA);
    float sB = seg_sum64(mB, ldm, colB, offB, eB, wid, lane, &degB);
    float h = sA / (float)max(degA, 1) + sB / (float)max(degB, 1) + bias[lane];
    if (relu) h = fmaxf(h, 0.f);
    out[(size_t)wid * 64 + lane] = h;
}

__device__ __forceinline__ float seg_sum32(
    const float* __restrict__ m, int ldm, int col,
    const int* __restrict__ off, const int* __restrict__ edges,
    int node, int lane, int* deg_out)
{
    int f = lane & 31, half = lane >> 5;
    int beg = off[node], end = off[node + 1];
    *deg_out = end - beg;
    float s = 0.f;
    for (int e = beg; e < end; e += 64) {
        int nb = min(64, end - e);
        int eidx = (lane < nb) ? edges[e + lane] : 0;
        for (int j = half; j < nb; j += 2) {
            int sa = __shfl(eidx, j);
            s += m[(size_t)sa * ldm + col + f];
        }
    }
    s += __shfl_xor(s, 32);
    return s;
}

__global__ __launch_bounds__(256) void k_gather32(
    const float* __restrict__ mA, int colA, const float* __restrict__ mB, int colB,
    const int* __restrict__ offA, const int* __restrict__ eA,
    const int* __restrict__ offB, const int* __restrict__ eB,
    const float* __restrict__ bias, float* __restrict__ out, int ldm)
{
    int wid  = (blockIdx.x * 256 + threadIdx.x) >> 6;
    int lane = threadIdx.x & 63;
    if (wid >= N_NODE) return;
    int f = lane & 31;
    int degA, degB;
    float sA = seg_sum32(mA, ldm, colA, offA, eA, wid, lane, &degA);
    float sB = seg_sum32(mB, ldm, colB, offB, eB, wid, lane, &degB);
    float h = sA / (float)max(degA, 1) + sB / (float)max(degB, 1) + bias[f];
    if (lane < 32) out[(size_t)wid * 32 + f] = h;
}

// ---------------- launcher ----------------
extern "C" void kernel_launch(void* const* d_in, const int* in_sizes, int n_in,
                              void* d_out, int out_size, void* d_ws, size_t ws_size,
                              hipStream_t stream)
{
    const float* xd = (const float*)d_in[0];
    const float* xg = (const float*)d_in[1];
    const int* dd_src = (const int*)d_in[2];  const int* dd_dst = (const int*)d_in[3];
    const int* dg_src = (const int*)d_in[4];  const int* dg_dst = (const int*)d_in[5];
    const int* gd_src = (const int*)d_in[6];  const int* gd_dst = (const int*)d_in[7];
    const int* gg_src = (const int*)d_in[8];  const int* gg_dst = (const int*)d_in[9];
    const float* W1dd = (const float*)d_in[10];
    const float* W1dg = (const float*)d_in[11];
    const float* W1gd = (const float*)d_in[12];
    const float* W1gg = (const float*)d_in[13];
    const float* b1d  = (const float*)d_in[14];
    const float* b1g  = (const float*)d_in[15];
    const float* W2dd = (const float*)d_in[16];
    const float* W2dg = (const float*)d_in[17];
    const float* W2gd = (const float*)d_in[18];
    const float* W2gg = (const float*)d_in[19];
    const float* b2d  = (const float*)d_in[20];
    const float* b2g  = (const float*)d_in[21];
    float* out = (float*)d_out;

    // workspace layout (~88 MB)
    int* part   = (int*)d_ws;                  // 256*128
    int* base_g = part + 256 * 128;            // 129
    int* gcur   = base_g + 132;                // 128
    int* off    = gcur + 128;                  // 4*(N_NODE+1)
    int* edges  = off + 4 * (N_NODE + 1);      // 4*NEDGE
    float* md1  = (float*)(edges + 4 * NEDGE); // 50000*128
    float* mg1  = md1 + (size_t)N_NODE * 128;  // 50000*128
    float* hd   = mg1 + (size_t)N_NODE * 128;  // 50000*64
    float* hg   = hd + (size_t)N_NODE * 64;    // 50000*64
    float* md2  = md1;
    float* mg2  = mg1;
    unsigned* gpart = (unsigned*)md1;          // 4*NEDGE uints, dead before GEMM1

    // ---- CSR build: LDS-only binning, no per-edge global atomics ----
    k_rangecount<<<256, 256, 0, stream>>>(dd_dst, gd_dst, dg_dst, gg_dst, part);
    k_rangebase<<<1, 128, 0, stream>>>(part, base_g, gcur);
    k_part<<<4 * NBLK1, 256, 0, stream>>>(
        dd_dst, dd_src, gd_dst, gd_src, dg_dst, dg_src, gg_dst, gg_src, gcur, gpart);
    k_csr<<<128, 256, 0, stream>>>(gpart, base_g, off, edges);

    const int* off_dd = off + 0 * (N_NODE + 1);
    const int* off_gd = off + 1 * (N_NODE + 1);
    const int* off_dg = off + 2 * (N_NODE + 1);
    const int* off_gg = off + 3 * (N_NODE + 1);
    const int* e_dd = edges + 0 * NEDGE;
    const int* e_gd = edges + 1 * NEDGE;
    const int* e_dg = edges + 2 * NEDGE;
    const int* e_gg = edges + 3 * NEDGE;

    // ---- layer 1 ----
    k_gemm_dual<128, 128><<<(N_NODE + 31) / 32, 256, 0, stream>>>(xd, W1dd, W1dg, md1, N_NODE);
    k_gemm_dual<128, 128><<<(N_NODE + 31) / 32, 256, 0, stream>>>(xg, W1gd, W1gg, mg1, N_NODE);
    k_gather64<<<(N_NODE * 64) / 256, 256, 0, stream>>>(
        md1, 0, mg1, 0, off_dd, e_dd, off_gd, e_gd, b1d, hd, 128, 1);
    k_gather64<<<(N_NODE * 64) / 256, 256, 0, stream>>>(
        md1, 64, mg1, 64, off_dg, e_dg, off_gg, e_gg, b1g, hg, 128, 1);

    // ---- layer 2 ----
    k_gemm_dual<64, 64><<<(N_NODE + 63) / 64, 256, 0, stream>>>(hd, W2dd, W2dg, md2, N_NODE);
    k_gemm_dual<64, 64><<<(N_NODE + 63) / 64, 256, 0, stream>>>(hg, W2gd, W2gg, mg2, N_NODE);
    k_gather32<<<(N_NODE * 64) / 256, 256, 0, stream>>>(
        md2, 0, mg2, 0, off_dd, e_dd, off_gd, e_gd, b2d, out, 64);
    k_gather32<<<(N_NODE * 64) / 256, 256, 0, stream>>>(
        md2, 32, mg2, 32, off_dg, e_dg, off_gg, e_gg, b2g, out + (size_t)N_NODE * 32, 64);
}

// Round 4
// 569.879 us; speedup vs baseline: 1.4409x; 1.0691x over previous
//
#include <hip/hip_runtime.h>
#include <hip/hip_bf16.h>

#define N_NODE 50000
#define NEDGE  600000
#define NRANGE 32
#define RSZ    1563      // ceil(N_NODE / NRANGE); 32*1563 = 50016 >= 50000
#define CAP    24576     // per-range staging capacity (avg 18750, sigma~135)
#define CHUNK  8192
#define NBLK1  74        // ceil(NEDGE / CHUNK)

typedef __hip_bfloat16 bf16;
struct __attribute__((aligned(8))) bh4 { bf16 a, b, c, d; };

// rel 0 = dd (dst=drug), 1 = gd (dst=drug), 2 = dg (dst=gene), 3 = gg (dst=gene)

// ---------- stage A: per-block range histograms (no global atomics) ----------
__global__ __launch_bounds__(256) void k_rangecount(
    const int* __restrict__ d0, const int* __restrict__ d1,
    const int* __restrict__ d2, const int* __restrict__ d3,
    int* __restrict__ part)
{
    __shared__ int h[4 * NRANGE];
    int tid = threadIdx.x;
    if (tid < 128) h[tid] = 0;
    __syncthreads();
    int stride = gridDim.x * 256;
    int gid = blockIdx.x * 256 + tid;
#pragma unroll
    for (int rel = 0; rel < 4; rel++) {
        const int* dp = rel == 0 ? d0 : rel == 1 ? d1 : rel == 2 ? d2 : d3;
        for (int e = gid; e < NEDGE; e += stride)
            atomicAdd(&h[rel * NRANGE + dp[e] / RSZ], 1);
    }
    __syncthreads();
    if (tid < 128) part[blockIdx.x * 128 + tid] = h[tid];
}

// ---------- stage B: reduce partials, scan to range bases ----------
__global__ __launch_bounds__(128) void k_rangebase(
    const int* __restrict__ part, int* __restrict__ base_g, int* __restrict__ gcur)
{
    __shared__ int tot[128];
    int t = threadIdx.x;
    int s = 0;
    for (int b = 0; b < 256; b++) s += part[b * 128 + t];
    tot[t] = s;
    __syncthreads();
    if (t == 0) {
        int run = 0;
        for (int i = 0; i < 128; i++) {
            int x = tot[i];
            base_g[i] = run;
            gcur[i]   = run;
            run += x;
        }
        base_g[128] = run;   // sentinel = 4*NEDGE
    }
}

// ---------- stage C: partition edges into (rel,range) buckets, LDS-staged ----------
__global__ __launch_bounds__(256) void k_part(
    const int* __restrict__ d0, const int* __restrict__ s0,
    const int* __restrict__ d1, const int* __restrict__ s1,
    const int* __restrict__ d2, const int* __restrict__ s2,
    const int* __restrict__ d3, const int* __restrict__ s3,
    int* __restrict__ gcur, unsigned* __restrict__ gpart)
{
    __shared__ int hcur[NRANGE];
    __shared__ int gbase[NRANGE];
    __shared__ unsigned buf[CHUNK];
    int bid = blockIdx.x;
    int rel = bid / NBLK1;
    int c   = bid - rel * NBLK1;
    int tid = threadIdx.x;
    const int* dp = rel == 0 ? d0 : rel == 1 ? d1 : rel == 2 ? d2 : d3;
    const int* sp = rel == 0 ? s0 : rel == 1 ? s1 : rel == 2 ? s2 : s3;
    int e0 = c * CHUNK;
    int e1 = min(e0 + CHUNK, NEDGE);
    int cnt_chunk = e1 - e0;

    if (tid < NRANGE) hcur[tid] = 0;
    __syncthreads();
    for (int e = e0 + tid; e < e1; e += 256)
        atomicAdd(&hcur[dp[e] / RSZ], 1);
    __syncthreads();
    int mycnt = (tid < NRANGE) ? hcur[tid] : 0;
    __syncthreads();
    if (tid == 0) {
        int run = 0;
        for (int i = 0; i < NRANGE; i++) { int x = hcur[i]; hcur[i] = run; run += x; }
    }
    __syncthreads();
    if (tid < NRANGE) gbase[tid] = atomicAdd(&gcur[rel * NRANGE + tid], mycnt);
    __syncthreads();
    for (int e = e0 + tid; e < e1; e += 256) {
        int d = dp[e];
        int u = d / RSZ;
        int p = atomicAdd(&hcur[u], 1);
        buf[p] = ((unsigned)(d - u * RSZ) << 16) | (unsigned)sp[e];
    }
    __syncthreads();
    for (int i = tid; i < cnt_chunk; i += 256) {
        int lo = 0, hi = NRANGE - 1;
        while (lo < hi) { int mid = (lo + hi) >> 1; if (hcur[mid] > i) hi = mid; else lo = mid + 1; }
        int beg = (lo == 0) ? 0 : hcur[lo - 1];
        gpart[gbase[lo] + (i - beg)] = buf[i];
    }
}

// ---------- stage D: per (rel,range) block -> final CSR (off + edges) ----------
__global__ __launch_bounds__(256) void k_csr(
    const unsigned* __restrict__ gpart, const int* __restrict__ base_g,
    int* __restrict__ off, int* __restrict__ edges)
{
    __shared__ int cur[RSZ];
    __shared__ unsigned short stg[CAP];
    __shared__ int sc[256];
    int bid = blockIdx.x;
    int rel = bid >> 5, r = bid & 31;
    int tid = threadIdx.x;
    int range0 = r * RSZ;
    int RS = min(RSZ, N_NODE - range0);
    int base_abs = base_g[bid];
    int count    = base_g[bid + 1] - base_abs;
    int base_rel = base_abs - rel * NEDGE;

    for (int i = tid; i < RSZ; i += 256) cur[i] = 0;
    __syncthreads();
    for (int i = tid; i < count; i += 256)
        atomicAdd(&cur[gpart[base_abs + i] >> 16], 1);
    __syncthreads();
    int vloc[7]; int run = 0;
#pragma unroll
    for (int j = 0; j < 7; j++) {
        int idx = tid * 7 + j;
        int x = (idx < RSZ) ? cur[idx] : 0;
        vloc[j] = x; run += x;
    }
    sc[tid] = run;
    __syncthreads();
    for (int d = 1; d < 256; d <<= 1) {
        int t = (tid >= d) ? sc[tid - d] : 0;
        __syncthreads();
        sc[tid] += t;
        __syncthreads();
    }
    int excl = sc[tid] - run;
    run = excl;
#pragma unroll
    for (int j = 0; j < 7; j++) {
        int idx = tid * 7 + j;
        if (idx < RSZ) { int x = vloc[j]; cur[idx] = run; run += x; }
    }
    __syncthreads();
    for (int i = tid; i < RS; i += 256)
        off[rel * (N_NODE + 1) + range0 + i] = base_rel + cur[i];
    if (r == NRANGE - 1 && tid == 0) off[rel * (N_NODE + 1) + N_NODE] = NEDGE;
    __syncthreads();
    if (count <= CAP) {
        for (int i = tid; i < count; i += 256) {
            unsigned v = gpart[base_abs + i];
            int p = atomicAdd(&cur[v >> 16], 1);
            stg[p] = (unsigned short)(v & 0xFFFFu);
        }
        __syncthreads();
        for (int i = tid; i < count; i += 256)
            edges[base_abs + i] = (int)stg[i];
    } else {
        for (int i = tid; i < count; i += 256) {
            unsigned v = gpart[base_abs + i];
            int p = atomicAdd(&cur[v >> 16], 1);
            edges[base_abs + p] = (int)(v & 0xFFFFu);
        }
    }
}

// ------- fused dual-weight GEMM: out(bf16) = X(fp32) @ [Wa | Wb] -------
template <int K, int NOUT>
__global__ __launch_bounds__(256) void k_gemm_dual(
    const float* __restrict__ X, const float* __restrict__ Wa,
    const float* __restrict__ Wb, bf16* __restrict__ out, int M)
{
    constexpr int N    = NOUT / 2;
    constexpr int TXC  = NOUT / 4;
    constexpr int TYC  = 256 / TXC;
    constexpr int ROWS = TYC * 4;
    __shared__ float Wc[K * NOUT];
    for (int i = threadIdx.x; i < K * NOUT; i += 256) {
        int k = i / NOUT, c = i - k * NOUT;
        Wc[i] = (c < N) ? Wa[k * N + c] : Wb[k * N + (c - N)];
    }
    __syncthreads();

    int tx = threadIdx.x % TXC, ty = threadIdx.x / TXC;
    int row0 = blockIdx.x * ROWS + ty * 4;
    int c0   = tx * 4;

    float acc[4][4] = {};
    const float* xr[4];
    bool rv[4];
#pragma unroll
    for (int i = 0; i < 4; i++) {
        int r = row0 + i;
        rv[i] = (r < M);
        xr[i] = X + (size_t)(rv[i] ? r : (M - 1)) * K;
    }

    for (int k = 0; k < K; k += 4) {
        float4 xv[4];
#pragma unroll
        for (int i = 0; i < 4; i++) xv[i] = *(const float4*)(xr[i] + k);
#pragma unroll
        for (int kk = 0; kk < 4; kk++) {
            float4 w = *(const float4*)&Wc[(k + kk) * NOUT + c0];
#pragma unroll
            for (int i = 0; i < 4; i++) {
                float xs = ((const float*)&xv[i])[kk];
                acc[i][0] += xs * w.x;
                acc[i][1] += xs * w.y;
                acc[i][2] += xs * w.z;
                acc[i][3] += xs * w.w;
            }
        }
    }
#pragma unroll
    for (int i = 0; i < 4; i++) {
        if (rv[i]) {
            bh4 v = { __float2bfloat16(acc[i][0]), __float2bfloat16(acc[i][1]),
                      __float2bfloat16(acc[i][2]), __float2bfloat16(acc[i][3]) };
            *(bh4*)(out + (size_t)(row0 + i) * NOUT + c0) = v;
        }
    }
}

// ---------------- segment-mean gathers (bf16 m, fp32 accumulate) ----------------
__device__ __forceinline__ float seg_sum64(
    const bf16* __restrict__ m, int ldm, int col,
    const int* __restrict__ off, const int* __restrict__ edges,
    int node, int lane, int* deg_out)
{
    int beg = off[node], end = off[node + 1];
    *deg_out = end - beg;
    float s = 0.f, s2 = 0.f;
    for (int e = beg; e < end; e += 64) {
        int nb = min(64, end - e);
        int eidx = (lane < nb) ? edges[e + lane] : 0;
        int j = 0;
        for (; j + 1 < nb; j += 2) {
            int sa = __shfl(eidx, j);
            int sb = __shfl(eidx, j + 1);
            s  += __bfloat162float(m[(size_t)sa * ldm + col + lane]);
            s2 += __bfloat162float(m[(size_t)sb * ldm + col + lane]);
        }
        if (j < nb) {
            int sa = __shfl(eidx, j);
            s += __bfloat162float(m[(size_t)sa * ldm + col + lane]);
        }
    }
    return s + s2;
}

__global__ __launch_bounds__(256) void k_gather64(
    const bf16* __restrict__ mA, int colA, const bf16* __restrict__ mB, int colB,
    const int* __restrict__ offA, const int* __restrict__ eA,
    const int* __restrict__ offB, const int* __restrict__ eB,
    const float* __restrict__ bias, float* __restrict__ out, int ldm, int relu)
{
    int wid  = (blockIdx.x * 256 + threadIdx.x) >> 6;
    int lane = threadIdx.x & 63;
    if (wid >= N_NODE) return;
    int degA, degB;
    float sA = seg_sum64(mA, ldm, colA, offA, eA, wid, lane, &degA);
    float sB = seg_sum64(mB, ldm, colB, offB, eB, wid, lane, &degB);
    float h = sA / (float)max(degA, 1) + sB / (float)max(degB, 1) + bias[lane];
    if (relu) h = fmaxf(h, 0.f);
    out[(size_t)wid * 64 + lane] = h;
}

__device__ __forceinline__ float seg_sum32(
    const bf16* __restrict__ m, int ldm, int col,
    const int* __restrict__ off, const int* __restrict__ edges,
    int node, int lane, int* deg_out)
{
    int f = lane & 31, half = lane >> 5;
    int beg = off[node], end = off[node + 1];
    *deg_out = end - beg;
    float s = 0.f;
    for (int e = beg; e < end; e += 64) {
        int nb = min(64, end - e);
        int eidx = (lane < nb) ? edges[e + lane] : 0;
        for (int j = half; j < nb; j += 2) {
            int sa = __shfl(eidx, j);
            s += __bfloat162float(m[(size_t)sa * ldm + col + f]);
        }
    }
    s += __shfl_xor(s, 32);
    return s;
}

__global__ __launch_bounds__(256) void k_gather32(
    const bf16* __restrict__ mA, int colA, const bf16* __restrict__ mB, int colB,
    const int* __restrict__ offA, const int* __restrict__ eA,
    const int* __restrict__ offB, const int* __restrict__ eB,
    const float* __restrict__ bias, float* __restrict__ out, int ldm)
{
    int wid  = (blockIdx.x * 256 + threadIdx.x) >> 6;
    int lane = threadIdx.x & 63;
    if (wid >= N_NODE) return;
    int f = lane & 31;
    int degA, degB;
    float sA = seg_sum32(mA, ldm, colA, offA, eA, wid, lane, &degA);
    float sB = seg_sum32(mB, ldm, colB, offB, eB, wid, lane, &degB);
    float h = sA / (float)max(degA, 1) + sB / (float)max(degB, 1) + bias[f];
    if (lane < 32) out[(size_t)wid * 32 + f] = h;
}

// ---------------- launcher ----------------
extern "C" void kernel_launch(void* const* d_in, const int* in_sizes, int n_in,
                              void* d_out, int out_size, void* d_ws, size_t ws_size,
                              hipStream_t stream)
{
    const float* xd = (const float*)d_in[0];
    const float* xg = (const float*)d_in[1];
    const int* dd_src = (const int*)d_in[2];  const int* dd_dst = (const int*)d_in[3];
    const int* dg_src = (const int*)d_in[4];  const int* dg_dst = (const int*)d_in[5];
    const int* gd_src = (const int*)d_in[6];  const int* gd_dst = (const int*)d_in[7];
    const int* gg_src = (const int*)d_in[8];  const int* gg_dst = (const int*)d_in[9];
    const float* W1dd = (const float*)d_in[10];
    const float* W1dg = (const float*)d_in[11];
    const float* W1gd = (const float*)d_in[12];
    const float* W1gg = (const float*)d_in[13];
    const float* b1d  = (const float*)d_in[14];
    const float* b1g  = (const float*)d_in[15];
    const float* W2dd = (const float*)d_in[16];
    const float* W2dg = (const float*)d_in[17];
    const float* W2gd = (const float*)d_in[18];
    const float* W2gg = (const float*)d_in[19];
    const float* b2d  = (const float*)d_in[20];
    const float* b2g  = (const float*)d_in[21];
    float* out = (float*)d_out;

    // workspace layout
    int* part   = (int*)d_ws;                  // 256*128
    int* base_g = part + 256 * 128;            // 129 (+pad)
    int* gcur   = base_g + 132;                // 128
    int* off    = gcur + 128;                  // 4*(N_NODE+1)
    int* edges  = off + 4 * (N_NODE + 1);      // 4*NEDGE
    bf16* md1   = (bf16*)(edges + 4 * NEDGE);  // 50000*128 bf16 (12.8 MB)
    bf16* mg1   = md1 + (size_t)N_NODE * 128;  // 50000*128 bf16
    float* hd   = (float*)(mg1 + (size_t)N_NODE * 128);  // 50000*64 fp32
    float* hg   = hd + (size_t)N_NODE * 64;              // 50000*64 fp32
    bf16* md2   = md1;   // layer-1 m dead after gather64 -> reuse
    bf16* mg2   = mg1;
    unsigned* gpart = (unsigned*)md1;          // 4*NEDGE uints, dead before GEMM1

    // ---- CSR build: LDS-only binning, no per-edge global atomics ----
    k_rangecount<<<256, 256, 0, stream>>>(dd_dst, gd_dst, dg_dst, gg_dst, part);
    k_rangebase<<<1, 128, 0, stream>>>(part, base_g, gcur);
    k_part<<<4 * NBLK1, 256, 0, stream>>>(
        dd_dst, dd_src, gd_dst, gd_src, dg_dst, dg_src, gg_dst, gg_src, gcur, gpart);
    k_csr<<<128, 256, 0, stream>>>(gpart, base_g, off, edges);

    const int* off_dd = off + 0 * (N_NODE + 1);
    const int* off_gd = off + 1 * (N_NODE + 1);
    const int* off_dg = off + 2 * (N_NODE + 1);
    const int* off_gg = off + 3 * (N_NODE + 1);
    const int* e_dd = edges + 0 * NEDGE;
    const int* e_gd = edges + 1 * NEDGE;
    const int* e_dg = edges + 2 * NEDGE;
    const int* e_gg = edges + 3 * NEDGE;

    // ---- layer 1 ----
    k_gemm_dual<128, 128><<<(N_NODE + 31) / 32, 256, 0, stream>>>(xd, W1dd, W1dg, md1, N_NODE);
    k_gemm_dual<128, 128><<<(N_NODE + 31) / 32, 256, 0, stream>>>(xg, W1gd, W1gg, mg1, N_NODE);
    k_gather64<<<(N_NODE * 64) / 256, 256, 0, stream>>>(
        md1, 0, mg1, 0, off_dd, e_dd, off_gd, e_gd, b1d, hd, 128, 1);
    k_gather64<<<(N_NODE * 64) / 256, 256, 0, stream>>>(
        md1, 64, mg1, 64, off_dg, e_dg, off_gg, e_gg, b1g, hg, 128, 1);

    // ---- layer 2 ----
    k_gemm_dual<64, 64><<<(N_NODE + 63) / 64, 256, 0, stream>>>(hd, W2dd, W2dg, md2, N_NODE);
    k_gemm_dual<64, 64><<<(N_NODE + 63) / 64, 256, 0, stream>>>(hg, W2gd, W2gg, mg2, N_NODE);
    k_gather32<<<(N_NODE * 64) / 256, 256, 0, stream>>>(
        md2, 0, mg2, 0, off_dd, e_dd, off_gd, e_gd, b2d, out, 64);
    k_gather32<<<(N_NODE * 64) / 256, 256, 0, stream>>>(
        md2, 32, mg2, 32, off_dg, e_dg, off_gg, e_gg, b2g, out + (size_t)N_NODE * 32, 64);
}

// Round 5
// 458.538 us; speedup vs baseline: 1.7907x; 1.2428x over previous
//
#include <hip/hip_runtime.h>
#include <hip/hip_bf16.h>

#define N_NODE 50000
#define NEDGE  600000
#define NRANGE 32
#define RSZ    1563      // ceil(N_NODE / NRANGE)
#define CAP    24576
#define CHUNK  8192
#define NBLK1  74        // ceil(NEDGE / CHUNK)

typedef __hip_bfloat16 bf16;
struct __attribute__((aligned(8))) bh4 { bf16 a, b, c, d; };
typedef __attribute__((ext_vector_type(8))) short short8;
typedef __attribute__((ext_vector_type(4))) float floatx4;

// rel 0 = dd (dst=drug), 1 = gd (dst=drug), 2 = dg (dst=gene), 3 = gg (dst=gene)

// ---------- stage A: per-block range histograms ----------
__global__ __launch_bounds__(256) void k_rangecount(
    const int* __restrict__ d0, const int* __restrict__ d1,
    const int* __restrict__ d2, const int* __restrict__ d3,
    int* __restrict__ part)
{
    __shared__ int h[4 * NRANGE];
    int tid = threadIdx.x;
    if (tid < 128) h[tid] = 0;
    __syncthreads();
    int stride = gridDim.x * 256;
    int gid = blockIdx.x * 256 + tid;
#pragma unroll
    for (int rel = 0; rel < 4; rel++) {
        const int* dp = rel == 0 ? d0 : rel == 1 ? d1 : rel == 2 ? d2 : d3;
        for (int e = gid; e < NEDGE; e += stride)
            atomicAdd(&h[rel * NRANGE + dp[e] / RSZ], 1);
    }
    __syncthreads();
    if (tid < 128) part[blockIdx.x * 128 + tid] = h[tid];
}

// ---------- stage B ----------
__global__ __launch_bounds__(128) void k_rangebase(
    const int* __restrict__ part, int* __restrict__ base_g, int* __restrict__ gcur)
{
    __shared__ int tot[128];
    int t = threadIdx.x;
    int s = 0;
    for (int b = 0; b < 256; b++) s += part[b * 128 + t];
    tot[t] = s;
    __syncthreads();
    if (t == 0) {
        int run = 0;
        for (int i = 0; i < 128; i++) {
            int x = tot[i];
            base_g[i] = run;
            gcur[i]   = run;
            run += x;
        }
        base_g[128] = run;
    }
}

// ---------- stage C: partition into (rel,range) buckets ----------
__global__ __launch_bounds__(256) void k_part(
    const int* __restrict__ d0, const int* __restrict__ s0,
    const int* __restrict__ d1, const int* __restrict__ s1,
    const int* __restrict__ d2, const int* __restrict__ s2,
    const int* __restrict__ d3, const int* __restrict__ s3,
    int* __restrict__ gcur, unsigned* __restrict__ gpart)
{
    __shared__ int hcur[NRANGE];
    __shared__ int gbase[NRANGE];
    __shared__ unsigned buf[CHUNK];
    int bid = blockIdx.x;
    int rel = bid / NBLK1;
    int c   = bid - rel * NBLK1;
    int tid = threadIdx.x;
    const int* dp = rel == 0 ? d0 : rel == 1 ? d1 : rel == 2 ? d2 : d3;
    const int* sp = rel == 0 ? s0 : rel == 1 ? s1 : rel == 2 ? s2 : s3;
    int e0 = c * CHUNK;
    int e1 = min(e0 + CHUNK, NEDGE);
    int cnt_chunk = e1 - e0;

    if (tid < NRANGE) hcur[tid] = 0;
    __syncthreads();
    for (int e = e0 + tid; e < e1; e += 256)
        atomicAdd(&hcur[dp[e] / RSZ], 1);
    __syncthreads();
    int mycnt = (tid < NRANGE) ? hcur[tid] : 0;
    __syncthreads();
    if (tid == 0) {
        int run = 0;
        for (int i = 0; i < NRANGE; i++) { int x = hcur[i]; hcur[i] = run; run += x; }
    }
    __syncthreads();
    if (tid < NRANGE) gbase[tid] = atomicAdd(&gcur[rel * NRANGE + tid], mycnt);
    __syncthreads();
    for (int e = e0 + tid; e < e1; e += 256) {
        int d = dp[e];
        int u = d / RSZ;
        int p = atomicAdd(&hcur[u], 1);
        buf[p] = ((unsigned)(d - u * RSZ) << 16) | (unsigned)sp[e];
    }
    __syncthreads();
    for (int i = tid; i < cnt_chunk; i += 256) {
        int lo = 0, hi = NRANGE - 1;
        while (lo < hi) { int mid = (lo + hi) >> 1; if (hcur[mid] > i) hi = mid; else lo = mid + 1; }
        int beg = (lo == 0) ? 0 : hcur[lo - 1];
        gpart[gbase[lo] + (i - beg)] = buf[i];
    }
}

// ---------- stage D: per (rel,range) block -> final CSR ----------
__global__ __launch_bounds__(256) void k_csr(
    const unsigned* __restrict__ gpart, const int* __restrict__ base_g,
    int* __restrict__ off, int* __restrict__ edges)
{
    __shared__ int cur[RSZ];
    __shared__ unsigned short stg[CAP];
    __shared__ int sc[256];
    int bid = blockIdx.x;
    int rel = bid >> 5, r = bid & 31;
    int tid = threadIdx.x;
    int range0 = r * RSZ;
    int RS = min(RSZ, N_NODE - range0);
    int base_abs = base_g[bid];
    int count    = base_g[bid + 1] - base_abs;
    int base_rel = base_abs - rel * NEDGE;

    for (int i = tid; i < RSZ; i += 256) cur[i] = 0;
    __syncthreads();
    for (int i = tid; i < count; i += 256)
        atomicAdd(&cur[gpart[base_abs + i] >> 16], 1);
    __syncthreads();
    int vloc[7]; int run = 0;
#pragma unroll
    for (int j = 0; j < 7; j++) {
        int idx = tid * 7 + j;
        int x = (idx < RSZ) ? cur[idx] : 0;
        vloc[j] = x; run += x;
    }
    sc[tid] = run;
    __syncthreads();
    for (int d = 1; d < 256; d <<= 1) {
        int t = (tid >= d) ? sc[tid - d] : 0;
        __syncthreads();
        sc[tid] += t;
        __syncthreads();
    }
    int excl = sc[tid] - run;
    run = excl;
#pragma unroll
    for (int j = 0; j < 7; j++) {
        int idx = tid * 7 + j;
        if (idx < RSZ) { int x = vloc[j]; cur[idx] = run; run += x; }
    }
    __syncthreads();
    for (int i = tid; i < RS; i += 256)
        off[rel * (N_NODE + 1) + range0 + i] = base_rel + cur[i];
    if (r == NRANGE - 1 && tid == 0) off[rel * (N_NODE + 1) + N_NODE] = NEDGE;
    __syncthreads();
    if (count <= CAP) {
        for (int i = tid; i < count; i += 256) {
            unsigned v = gpart[base_abs + i];
            int p = atomicAdd(&cur[v >> 16], 1);
            stg[p] = (unsigned short)(v & 0xFFFFu);
        }
        __syncthreads();
        for (int i = tid; i < count; i += 256)
            edges[base_abs + i] = (int)stg[i];
    } else {
        for (int i = tid; i < count; i += 256) {
            unsigned v = gpart[base_abs + i];
            int p = atomicAdd(&cur[v >> 16], 1);
            edges[base_abs + p] = (int)(v & 0xFFFFu);
        }
    }
}

// ---------- cast xd,xg (fp32) -> bf16 ----------
__global__ __launch_bounds__(256) void k_cast(
    const float* __restrict__ a, const float* __restrict__ b,
    bf16* __restrict__ ao, bf16* __restrict__ bo, int n4)
{
    int i = blockIdx.x * 256 + threadIdx.x;
    if (i >= n4) return;
    float4 va = ((const float4*)a)[i];
    float4 vb = ((const float4*)b)[i];
    bh4 oa = { __float2bfloat16(va.x), __float2bfloat16(va.y),
               __float2bfloat16(va.z), __float2bfloat16(va.w) };
    bh4 ob = { __float2bfloat16(vb.x), __float2bfloat16(vb.y),
               __float2bfloat16(vb.z), __float2bfloat16(vb.w) };
    ((bh4*)ao)[i] = oa;
    ((bh4*)bo)[i] = ob;
}

// ---------- MFMA dual-weight GEMM: out(bf16) = X(bf16) @ [Wa | Wb](fp32->bf16) ----------
// Per block: 4 waves x 16 rows = 64 rows, all NOUT cols. mfma_f32_16x16x32_bf16.
// A-frag: lane(q,m): X[row0+m][kc*32+q*8 .. +7]. B-frag swizzled in LDS.
template <int K, int NOUT>
__global__ __launch_bounds__(256) void k_gemm_mfma(
    const bf16* __restrict__ X, const float* __restrict__ Wa,
    const float* __restrict__ Wb, bf16* __restrict__ out, int M)
{
    constexpr int NB  = NOUT / 16;
    constexpr int KC  = K / 32;
    constexpr int NH  = NOUT / 2;
    constexpr int NBL = (NB == 8) ? 3 : 2;
    __shared__ short Wl[KC * NB * 512];

    int tid = threadIdx.x;
    for (int i = tid; i < KC * NB * 512; i += 256) {
        int j  = i & 7;
        int n  = (i >> 3) & 15;
        int q  = (i >> 7) & 3;
        int nb = (i >> 9) & (NB - 1);
        int kc = i >> (9 + NBL);
        int k  = kc * 32 + q * 8 + j;
        int c  = nb * 16 + n;
        float w = (c < NH) ? Wa[k * NH + c] : Wb[k * NH + (c - NH)];
        bf16 h = __float2bfloat16(w);
        Wl[i] = *(short*)&h;
    }
    __syncthreads();

    int lane = tid & 63, wv = tid >> 6;
    int q = lane >> 4, lidx = lane & 15;
    int row0 = blockIdx.x * 64 + wv * 16;
    int rowA = min(row0 + lidx, M - 1);
    const short* Xs = (const short*)X;

    floatx4 acc[NB];
#pragma unroll
    for (int nb = 0; nb < NB; nb++) acc[nb] = (floatx4){0.f, 0.f, 0.f, 0.f};

#pragma unroll
    for (int kc = 0; kc < KC; kc++) {
        short8 a = *(const short8*)(Xs + (size_t)rowA * K + kc * 32 + q * 8);
#pragma unroll
        for (int nb = 0; nb < NB; nb++) {
            short8 b = *(const short8*)&Wl[((kc * NB + nb) * 64 + lane) * 8];
            acc[nb] = __builtin_amdgcn_mfma_f32_16x16x32_bf16(a, b, acc[nb], 0, 0, 0);
        }
    }
#pragma unroll
    for (int nb = 0; nb < NB; nb++) {
#pragma unroll
        for (int r = 0; r < 4; r++) {
            int row = row0 + q * 4 + r;
            if (row < M)
                out[(size_t)row * NOUT + nb * 16 + lidx] = __float2bfloat16(acc[nb][r]);
        }
    }
}

// ---------- segment-mean gather, 64 features: 16 lanes/edge, 4 edges/instr ----------
__device__ __forceinline__ void seg_sum64(
    const bf16* __restrict__ m, int ldm, int col,
    const int* __restrict__ off, const int* __restrict__ edges,
    int node, int lane, int lgrp, int lidx, float s[4], int* deg_out)
{
    int beg = off[node], end = off[node + 1];
    *deg_out = end - beg;
    const unsigned short* mb = (const unsigned short*)m;
    for (int e = beg; e < end; e += 64) {
        int nb = min(64, end - e);
        int eidx = (lane < nb) ? edges[e + lane] : 0;
        for (int j = 0; j < nb; j += 4) {
            int sa   = __shfl(eidx, j + lgrp);
            float vm = (j + lgrp < nb) ? 1.f : 0.f;
            uint2 w  = *(const uint2*)(mb + (size_t)sa * ldm + col + lidx * 4);
            s[0] += vm * __uint_as_float(w.x << 16);
            s[1] += vm * __uint_as_float(w.x & 0xFFFF0000u);
            s[2] += vm * __uint_as_float(w.y << 16);
            s[3] += vm * __uint_as_float(w.y & 0xFFFF0000u);
        }
    }
}

__global__ __launch_bounds__(256) void k_gather64(
    const bf16* __restrict__ mA, int colA, const bf16* __restrict__ mB, int colB,
    const int* __restrict__ offA, const int* __restrict__ eA,
    const int* __restrict__ offB, const int* __restrict__ eB,
    const float* __restrict__ bias, bf16* __restrict__ out, int ldm, int relu)
{
    int wid  = (blockIdx.x * 256 + threadIdx.x) >> 6;
    int lane = threadIdx.x & 63;
    if (wid >= N_NODE) return;
    int lgrp = lane >> 4, lidx = lane & 15;
    float sA[4] = {0.f, 0.f, 0.f, 0.f}, sB[4] = {0.f, 0.f, 0.f, 0.f};
    int degA, degB;
    seg_sum64(mA, ldm, colA, offA, eA, wid, lane, lgrp, lidx, sA, &degA);
    seg_sum64(mB, ldm, colB, offB, eB, wid, lane, lgrp, lidx, sB, &degB);
#pragma unroll
    for (int k = 0; k < 4; k++) {
        sA[k] += __shfl_xor(sA[k], 16); sA[k] += __shfl_xor(sA[k], 32);
        sB[k] += __shfl_xor(sB[k], 16); sB[k] += __shfl_xor(sB[k], 32);
    }
    if (lane < 16) {
        float ia = 1.f / (float)max(degA, 1), ib = 1.f / (float)max(degB, 1);
        bh4 v;
        float h0 = sA[0] * ia + sB[0] * ib + bias[lidx * 4 + 0];
        float h1 = sA[1] * ia + sB[1] * ib + bias[lidx * 4 + 1];
        float h2 = sA[2] * ia + sB[2] * ib + bias[lidx * 4 + 2];
        float h3 = sA[3] * ia + sB[3] * ib + bias[lidx * 4 + 3];
        if (relu) { h0 = fmaxf(h0, 0.f); h1 = fmaxf(h1, 0.f); h2 = fmaxf(h2, 0.f); h3 = fmaxf(h3, 0.f); }
        v.a = __float2bfloat16(h0); v.b = __float2bfloat16(h1);
        v.c = __float2bfloat16(h2); v.d = __float2bfloat16(h3);
        *(bh4*)(out + (size_t)wid * 64 + lidx * 4) = v;
    }
}

// ---------- segment-mean gather, 32 features: 8 lanes/edge, 8 edges/instr ----------
__device__ __forceinline__ void seg_sum32(
    const bf16* __restrict__ m, int ldm, int col,
    const int* __restrict__ off, const int* __restrict__ edges,
    int node, int lane, int lgrp, int lidx, float s[4], int* deg_out)
{
    int beg = off[node], end = off[node + 1];
    *deg_out = end - beg;
    const unsigned short* mb = (const unsigned short*)m;
    for (int e = beg; e < end; e += 64) {
        int nb = min(64, end - e);
        int eidx = (lane < nb) ? edges[e + lane] : 0;
        for (int j = 0; j < nb; j += 8) {
            int sa   = __shfl(eidx, j + lgrp);
            float vm = (j + lgrp < nb) ? 1.f : 0.f;
            uint2 w  = *(const uint2*)(mb + (size_t)sa * ldm + col + lidx * 4);
            s[0] += vm * __uint_as_float(w.x << 16);
            s[1] += vm * __uint_as_float(w.x & 0xFFFF0000u);
            s[2] += vm * __uint_as_float(w.y << 16);
            s[3] += vm * __uint_as_float(w.y & 0xFFFF0000u);
        }
    }
}

__global__ __launch_bounds__(256) void k_gather32(
    const bf16* __restrict__ mA, int colA, const bf16* __restrict__ mB, int colB,
    const int* __restrict__ offA, const int* __restrict__ eA,
    const int* __restrict__ offB, const int* __restrict__ eB,
    const float* __restrict__ bias, float* __restrict__ out, int ldm)
{
    int wid  = (blockIdx.x * 256 + threadIdx.x) >> 6;
    int lane = threadIdx.x & 63;
    if (wid >= N_NODE) return;
    int lgrp = lane >> 3, lidx = lane & 7;
    float sA[4] = {0.f, 0.f, 0.f, 0.f}, sB[4] = {0.f, 0.f, 0.f, 0.f};
    int degA, degB;
    seg_sum32(mA, ldm, colA, offA, eA, wid, lane, lgrp, lidx, sA, &degA);
    seg_sum32(mB, ldm, colB, offB, eB, wid, lane, lgrp, lidx, sB, &degB);
#pragma unroll
    for (int k = 0; k < 4; k++) {
        sA[k] += __shfl_xor(sA[k], 8); sA[k] += __shfl_xor(sA[k], 16); sA[k] += __shfl_xor(sA[k], 32);
        sB[k] += __shfl_xor(sB[k], 8); sB[k] += __shfl_xor(sB[k], 16); sB[k] += __shfl_xor(sB[k], 32);
    }
    if (lane < 8) {
        float ia = 1.f / (float)max(degA, 1), ib = 1.f / (float)max(degB, 1);
        float4 v;
        v.x = sA[0] * ia + sB[0] * ib + bias[lidx * 4 + 0];
        v.y = sA[1] * ia + sB[1] * ib + bias[lidx * 4 + 1];
        v.z = sA[2] * ia + sB[2] * ib + bias[lidx * 4 + 2];
        v.w = sA[3] * ia + sB[3] * ib + bias[lidx * 4 + 3];
        *(float4*)(out + (size_t)wid * 32 + lidx * 4) = v;
    }
}

// ---------------- launcher ----------------
extern "C" void kernel_launch(void* const* d_in, const int* in_sizes, int n_in,
                              void* d_out, int out_size, void* d_ws, size_t ws_size,
                              hipStream_t stream)
{
    const float* xd = (const float*)d_in[0];
    const float* xg = (const float*)d_in[1];
    const int* dd_src = (const int*)d_in[2];  const int* dd_dst = (const int*)d_in[3];
    const int* dg_src = (const int*)d_in[4];  const int* dg_dst = (const int*)d_in[5];
    const int* gd_src = (const int*)d_in[6];  const int* gd_dst = (const int*)d_in[7];
    const int* gg_src = (const int*)d_in[8];  const int* gg_dst = (const int*)d_in[9];
    const float* W1dd = (const float*)d_in[10];
    const float* W1dg = (const float*)d_in[11];
    const float* W1gd = (const float*)d_in[12];
    const float* W1gg = (const float*)d_in[13];
    const float* b1d  = (const float*)d_in[14];
    const float* b1g  = (const float*)d_in[15];
    const float* W2dd = (const float*)d_in[16];
    const float* W2dg = (const float*)d_in[17];
    const float* W2gd = (const float*)d_in[18];
    const float* W2gg = (const float*)d_in[19];
    const float* b2d  = (const float*)d_in[20];
    const float* b2g  = (const float*)d_in[21];
    float* out = (float*)d_out;

    // workspace layout (~75 MB)
    int* part   = (int*)d_ws;                  // 256*128
    int* base_g = part + 256 * 128;            // 129 (+pad)
    int* gcur   = base_g + 132;                // 128
    int* off    = gcur + 128;                  // 4*(N_NODE+1)
    int* edges  = off + 4 * (N_NODE + 1);      // 4*NEDGE
    bf16* xdb   = (bf16*)(edges + 4 * NEDGE);  // 50000*128 bf16
    bf16* xgb   = xdb + (size_t)N_NODE * 128;
    bf16* md1   = xgb + (size_t)N_NODE * 128;  // 50000*128 bf16
    bf16* mg1   = md1 + (size_t)N_NODE * 128;
    bf16* hd    = mg1 + (size_t)N_NODE * 128;  // 50000*64 bf16
    bf16* hg    = hd + (size_t)N_NODE * 64;
    bf16* md2   = md1;   // layer-1 m dead after gather64 -> reuse
    bf16* mg2   = mg1;
    unsigned* gpart = (unsigned*)md1;          // 2.4M uints (9.6 MB), dead before GEMM1

    // ---- CSR build ----
    k_rangecount<<<256, 256, 0, stream>>>(dd_dst, gd_dst, dg_dst, gg_dst, part);
    k_rangebase<<<1, 128, 0, stream>>>(part, base_g, gcur);
    k_part<<<4 * NBLK1, 256, 0, stream>>>(
        dd_dst, dd_src, gd_dst, gd_src, dg_dst, dg_src, gg_dst, gg_src, gcur, gpart);
    k_csr<<<128, 256, 0, stream>>>(gpart, base_g, off, edges);

    // ---- cast inputs to bf16 ----
    k_cast<<<(N_NODE * 128 / 4 + 255) / 256, 256, 0, stream>>>(
        xd, xg, xdb, xgb, N_NODE * 128 / 4);

    const int* off_dd = off + 0 * (N_NODE + 1);
    const int* off_gd = off + 1 * (N_NODE + 1);
    const int* off_dg = off + 2 * (N_NODE + 1);
    const int* off_gg = off + 3 * (N_NODE + 1);
    const int* e_dd = edges + 0 * NEDGE;
    const int* e_gd = edges + 1 * NEDGE;
    const int* e_dg = edges + 2 * NEDGE;
    const int* e_gg = edges + 3 * NEDGE;

    int gemm_grid = (N_NODE + 63) / 64;

    // ---- layer 1 ----
    k_gemm_mfma<128, 128><<<gemm_grid, 256, 0, stream>>>(xdb, W1dd, W1dg, md1, N_NODE);
    k_gemm_mfma<128, 128><<<gemm_grid, 256, 0, stream>>>(xgb, W1gd, W1gg, mg1, N_NODE);
    k_gather64<<<(N_NODE * 64) / 256, 256, 0, stream>>>(
        md1, 0, mg1, 0, off_dd, e_dd, off_gd, e_gd, b1d, hd, 128, 1);
    k_gather64<<<(N_NODE * 64) / 256, 256, 0, stream>>>(
        md1, 64, mg1, 64, off_dg, e_dg, off_gg, e_gg, b1g, hg, 128, 1);

    // ---- layer 2 ----
    k_gemm_mfma<64, 64><<<gemm_grid, 256, 0, stream>>>(hd, W2dd, W2dg, md2, N_NODE);
    k_gemm_mfma<64, 64><<<gemm_grid, 256, 0, stream>>>(hg, W2gd, W2gg, mg2, N_NODE);
    k_gather32<<<(N_NODE * 64) / 256, 256, 0, stream>>>(
        md2, 0, mg2, 0, off_dd, e_dd, off_gd, e_gd, b2d, out, 64);
    k_gather32<<<(N_NODE * 64) / 256, 256, 0, stream>>>(
        md2, 32, mg2, 32, off_dg, e_dg, off_gg, e_gg, b2g, out + (size_t)N_NODE * 32, 64);
}

// Round 6
// 398.183 us; speedup vs baseline: 2.0622x; 1.1516x over previous
//
#include <hip/hip_runtime.h>
#include <hip/hip_bf16.h>

#define N_NODE 50000
#define NEDGE  600000
#define NRANGE 128
#define RSZ    391       // ceil(N_NODE / NRANGE); 128*391 = 50048 >= 50000
#define CAPB   6144      // slot capacity per (rel,range): mean 4688, sigma ~68 -> +21 sigma
#define CHUNK  4096
#define NBLK1  147       // ceil(NEDGE / CHUNK)

typedef __hip_bfloat16 bf16;
struct __attribute__((aligned(8))) bh4 { bf16 a, b, c, d; };
typedef __attribute__((ext_vector_type(8))) short short8;
typedef __attribute__((ext_vector_type(4))) float floatx4;

// rel 0 = dd (dst=drug), 1 = gd (dst=drug), 2 = dg (dst=gene), 3 = gg (dst=gene)
// key packing: (bucket:7 << 25) | (dst_local:9 << 16) | (src:16)

// ---------- stage A: partition edges into fixed-capacity (rel,range) slots ----------
__global__ __launch_bounds__(256) void k_part(
    const int* __restrict__ d0, const int* __restrict__ s0,
    const int* __restrict__ d1, const int* __restrict__ s1,
    const int* __restrict__ d2, const int* __restrict__ s2,
    const int* __restrict__ d3, const int* __restrict__ s3,
    int* __restrict__ gcur, unsigned* __restrict__ gpart)
{
    __shared__ int hcur[NRANGE];     // hist -> start -> cursor
    __shared__ int delta[NRANGE];    // slotbase + resv - start
    __shared__ int sc[256];
    __shared__ unsigned buf[CHUNK];
    int bid = blockIdx.x;
    int rel = bid / NBLK1;
    int c   = bid - rel * NBLK1;
    int tid = threadIdx.x;
    const int* dp = rel == 0 ? d0 : rel == 1 ? d1 : rel == 2 ? d2 : d3;
    const int* sp = rel == 0 ? s0 : rel == 1 ? s1 : rel == 2 ? s2 : s3;
    int e0 = c * CHUNK;
    int e1 = min(e0 + CHUNK, NEDGE);
    int cnt_chunk = e1 - e0;

    if (tid < NRANGE) hcur[tid] = 0;
    __syncthreads();
    for (int e = e0 + tid; e < e1; e += 256)
        atomicAdd(&hcur[dp[e] / RSZ], 1);
    __syncthreads();
    // exclusive scan of 128 hist entries (Hillis-Steele on first 128 threads)
    int v = (tid < NRANGE) ? hcur[tid] : 0;
    sc[tid] = v;
    __syncthreads();
    for (int d = 1; d < NRANGE; d <<= 1) {
        int t = (tid >= d && tid < NRANGE) ? sc[tid - d] : 0;
        __syncthreads();
        sc[tid] += t;
        __syncthreads();
    }
    if (tid < NRANGE) {
        int start = sc[tid] - v;
        int bg    = rel * NRANGE + tid;
        int resv  = atomicAdd(&gcur[bg], v);
        delta[tid] = bg * CAPB + resv - start;
        hcur[tid]  = start;          // binning cursor
    }
    __syncthreads();
    // bin packed keys into LDS at chunk-local positions
    for (int e = e0 + tid; e < e1; e += 256) {
        int d = dp[e];
        int b = d / RSZ;
        int p = atomicAdd(&hcur[b], 1);
        buf[p] = ((unsigned)b << 25) | ((unsigned)(d - b * RSZ) << 16) | (unsigned)sp[e];
    }
    __syncthreads();
    // coalesced write-out: position = delta[bucket] + i
    for (int i = tid; i < cnt_chunk; i += 256) {
        unsigned key = buf[i];
        gpart[delta[key >> 25] + i] = key;
    }
}

// ---------- stage B: per-rel exclusive scan of 512 bucket counts ----------
__global__ __launch_bounds__(512) void k_base(
    const int* __restrict__ gcur, int* __restrict__ base_rel)
{
    __shared__ int sc[512];
    int t = threadIdx.x;
    int v = gcur[t];
    sc[t] = v;
    __syncthreads();
    int loc = t & (NRANGE - 1);
    for (int d = 1; d < NRANGE; d <<= 1) {
        int x = (loc >= d) ? sc[t - d] : 0;
        __syncthreads();
        sc[t] += x;
        __syncthreads();
    }
    base_rel[t] = sc[t] - v;   // exclusive within rel
}

// ---------- stage C: per (rel,range) block -> final CSR (off + edges) ----------
__global__ __launch_bounds__(256) void k_csr(
    const unsigned* __restrict__ gpart, const int* __restrict__ gcnt,
    const int* __restrict__ base_rel, int* __restrict__ off, int* __restrict__ edges)
{
    __shared__ int cur[RSZ];
    __shared__ unsigned short stg[CAPB];
    __shared__ int sc[256];
    int bid = blockIdx.x;
    int rel = bid >> 7, r = bid & (NRANGE - 1);
    int tid = threadIdx.x;
    int range0 = r * RSZ;
    int RS = min(RSZ, N_NODE - range0);
    if (RS < 0) RS = 0;
    int count = gcnt[bid];
    int base  = base_rel[bid];               // rel-local edge base
    size_t slot0 = (size_t)bid * CAPB;

    for (int i = tid; i < RSZ; i += 256) cur[i] = 0;
    __syncthreads();
    for (int i = tid; i < count; i += 256)
        atomicAdd(&cur[(gpart[slot0 + i] >> 16) & 0x1FF], 1);
    __syncthreads();
    int vloc[2]; int run = 0;
#pragma unroll
    for (int j = 0; j < 2; j++) {
        int idx = tid * 2 + j;
        int x = (idx < RSZ) ? cur[idx] : 0;
        vloc[j] = x; run += x;
    }
    sc[tid] = run;
    __syncthreads();
    for (int d = 1; d < 256; d <<= 1) {
        int t = (tid >= d) ? sc[tid - d] : 0;
        __syncthreads();
        sc[tid] += t;
        __syncthreads();
    }
    int excl = sc[tid] - run;
    run = excl;
#pragma unroll
    for (int j = 0; j < 2; j++) {
        int idx = tid * 2 + j;
        if (idx < RSZ) { int x = vloc[j]; cur[idx] = run; run += x; }
    }
    __syncthreads();
    for (int i = tid; i < RS; i += 256)
        off[rel * (N_NODE + 1) + range0 + i] = base + cur[i];
    if (r == NRANGE - 1 && tid == 0) off[rel * (N_NODE + 1) + N_NODE] = NEDGE;
    __syncthreads();
    for (int i = tid; i < count; i += 256) {
        unsigned key = gpart[slot0 + i];
        int p = atomicAdd(&cur[(key >> 16) & 0x1FF], 1);
        stg[p] = (unsigned short)(key & 0xFFFFu);
    }
    __syncthreads();
    for (int i = tid; i < count; i += 256)
        edges[rel * NEDGE + base + i] = (int)stg[i];
}

// ---------- cast xd,xg (fp32) -> bf16 ----------
__global__ __launch_bounds__(256) void k_cast(
    const float* __restrict__ a, const float* __restrict__ b,
    bf16* __restrict__ ao, bf16* __restrict__ bo, int n4)
{
    int i = blockIdx.x * 256 + threadIdx.x;
    if (i >= n4) return;
    float4 va = ((const float4*)a)[i];
    float4 vb = ((const float4*)b)[i];
    bh4 oa = { __float2bfloat16(va.x), __float2bfloat16(va.y),
               __float2bfloat16(va.z), __float2bfloat16(va.w) };
    bh4 ob = { __float2bfloat16(vb.x), __float2bfloat16(vb.y),
               __float2bfloat16(vb.z), __float2bfloat16(vb.w) };
    ((bh4*)ao)[i] = oa;
    ((bh4*)bo)[i] = ob;
}

// ---------- MFMA dual-weight GEMM: out(bf16) = X(bf16) @ [Wa | Wb] ----------
template <int K, int NOUT>
__global__ __launch_bounds__(256) void k_gemm_mfma(
    const bf16* __restrict__ X, const float* __restrict__ Wa,
    const float* __restrict__ Wb, bf16* __restrict__ out, int M)
{
    constexpr int NB  = NOUT / 16;
    constexpr int KC  = K / 32;
    constexpr int NH  = NOUT / 2;
    constexpr int NBL = (NB == 8) ? 3 : 2;
    __shared__ short Wl[KC * NB * 512];

    int tid = threadIdx.x;
    for (int i = tid; i < KC * NB * 512; i += 256) {
        int j  = i & 7;
        int n  = (i >> 3) & 15;
        int q  = (i >> 7) & 3;
        int nb = (i >> 9) & (NB - 1);
        int kc = i >> (9 + NBL);
        int k  = kc * 32 + q * 8 + j;
        int c  = nb * 16 + n;
        float w = (c < NH) ? Wa[k * NH + c] : Wb[k * NH + (c - NH)];
        bf16 h = __float2bfloat16(w);
        Wl[i] = *(short*)&h;
    }
    __syncthreads();

    int lane = tid & 63, wv = tid >> 6;
    int q = lane >> 4, lidx = lane & 15;
    int row0 = blockIdx.x * 64 + wv * 16;
    int rowA = min(row0 + lidx, M - 1);
    const short* Xs = (const short*)X;

    floatx4 acc[NB];
#pragma unroll
    for (int nb = 0; nb < NB; nb++) acc[nb] = (floatx4){0.f, 0.f, 0.f, 0.f};

#pragma unroll
    for (int kc = 0; kc < KC; kc++) {
        short8 a = *(const short8*)(Xs + (size_t)rowA * K + kc * 32 + q * 8);
#pragma unroll
        for (int nb = 0; nb < NB; nb++) {
            short8 b = *(const short8*)&Wl[((kc * NB + nb) * 64 + lane) * 8];
            acc[nb] = __builtin_amdgcn_mfma_f32_16x16x32_bf16(a, b, acc[nb], 0, 0, 0);
        }
    }
#pragma unroll
    for (int nb = 0; nb < NB; nb++) {
#pragma unroll
        for (int r = 0; r < 4; r++) {
            int row = row0 + q * 4 + r;
            if (row < M)
                out[(size_t)row * NOUT + nb * 16 + lidx] = __float2bfloat16(acc[nb][r]);
        }
    }
}

// ---------- segment-mean gather, 64 features: 16 lanes/edge, 4 edges/instr ----------
__device__ __forceinline__ void seg_sum64(
    const bf16* __restrict__ m, int ldm, int col,
    const int* __restrict__ off, const int* __restrict__ edges,
    int node, int lane, int lgrp, int lidx, float s[4], int* deg_out)
{
    int beg = off[node], end = off[node + 1];
    *deg_out = end - beg;
    const unsigned short* mb = (const unsigned short*)m;
    for (int e = beg; e < end; e += 64) {
        int nb = min(64, end - e);
        int eidx = (lane < nb) ? edges[e + lane] : 0;
        for (int j = 0; j < nb; j += 4) {
            int sa   = __shfl(eidx, j + lgrp);
            float vm = (j + lgrp < nb) ? 1.f : 0.f;
            uint2 w  = *(const uint2*)(mb + (size_t)sa * ldm + col + lidx * 4);
            s[0] += vm * __uint_as_float(w.x << 16);
            s[1] += vm * __uint_as_float(w.x & 0xFFFF0000u);
            s[2] += vm * __uint_as_float(w.y << 16);
            s[3] += vm * __uint_as_float(w.y & 0xFFFF0000u);
        }
    }
}

__global__ __launch_bounds__(256) void k_gather64(
    const bf16* __restrict__ mA, int colA, const bf16* __restrict__ mB, int colB,
    const int* __restrict__ offA, const int* __restrict__ eA,
    const int* __restrict__ offB, const int* __restrict__ eB,
    const float* __restrict__ bias, bf16* __restrict__ out, int ldm, int relu)
{
    int wid  = (blockIdx.x * 256 + threadIdx.x) >> 6;
    int lane = threadIdx.x & 63;
    if (wid >= N_NODE) return;
    int lgrp = lane >> 4, lidx = lane & 15;
    float sA[4] = {0.f, 0.f, 0.f, 0.f}, sB[4] = {0.f, 0.f, 0.f, 0.f};
    int degA, degB;
    seg_sum64(mA, ldm, colA, offA, eA, wid, lane, lgrp, lidx, sA, &degA);
    seg_sum64(mB, ldm, colB, offB, eB, wid, lane, lgrp, lidx, sB, &degB);
#pragma unroll
    for (int k = 0; k < 4; k++) {
        sA[k] += __shfl_xor(sA[k], 16); sA[k] += __shfl_xor(sA[k], 32);
        sB[k] += __shfl_xor(sB[k], 16); sB[k] += __shfl_xor(sB[k], 32);
    }
    if (lane < 16) {
        float ia = 1.f / (float)max(degA, 1), ib = 1.f / (float)max(degB, 1);
        bh4 v;
        float h0 = sA[0] * ia + sB[0] * ib + bias[lidx * 4 + 0];
        float h1 = sA[1] * ia + sB[1] * ib + bias[lidx * 4 + 1];
        float h2 = sA[2] * ia + sB[2] * ib + bias[lidx * 4 + 2];
        float h3 = sA[3] * ia + sB[3] * ib + bias[lidx * 4 + 3];
        if (relu) { h0 = fmaxf(h0, 0.f); h1 = fmaxf(h1, 0.f); h2 = fmaxf(h2, 0.f); h3 = fmaxf(h3, 0.f); }
        v.a = __float2bfloat16(h0); v.b = __float2bfloat16(h1);
        v.c = __float2bfloat16(h2); v.d = __float2bfloat16(h3);
        *(bh4*)(out + (size_t)wid * 64 + lidx * 4) = v;
    }
}

// ---------- segment-mean gather, 32 features: 8 lanes/edge, 8 edges/instr ----------
__device__ __forceinline__ void seg_sum32(
    const bf16* __restrict__ m, int ldm, int col,
    const int* __restrict__ off, const int* __restrict__ edges,
    int node, int lane, int lgrp, int lidx, float s[4], int* deg_out)
{
    int beg = off[node], end = off[node + 1];
    *deg_out = end - beg;
    const unsigned short* mb = (const unsigned short*)m;
    for (int e = beg; e < end; e += 64) {
        int nb = min(64, end - e);
        int eidx = (lane < nb) ? edges[e + lane] : 0;
        for (int j = 0; j < nb; j += 8) {
            int sa   = __shfl(eidx, j + lgrp);
            float vm = (j + lgrp < nb) ? 1.f : 0.f;
            uint2 w  = *(const uint2*)(mb + (size_t)sa * ldm + col + lidx * 4);
            s[0] += vm * __uint_as_float(w.x << 16);
            s[1] += vm * __uint_as_float(w.x & 0xFFFF0000u);
            s[2] += vm * __uint_as_float(w.y << 16);
            s[3] += vm * __uint_as_float(w.y & 0xFFFF0000u);
        }
    }
}

__global__ __launch_bounds__(256) void k_gather32(
    const bf16* __restrict__ mA, int colA, const bf16* __restrict__ mB, int colB,
    const int* __restrict__ offA, const int* __restrict__ eA,
    const int* __restrict__ offB, const int* __restrict__ eB,
    const float* __restrict__ bias, float* __restrict__ out, int ldm)
{
    int wid  = (blockIdx.x * 256 + threadIdx.x) >> 6;
    int lane = threadIdx.x & 63;
    if (wid >= N_NODE) return;
    int lgrp = lane >> 3, lidx = lane & 7;
    float sA[4] = {0.f, 0.f, 0.f, 0.f}, sB[4] = {0.f, 0.f, 0.f, 0.f};
    int degA, degB;
    seg_sum32(mA, ldm, colA, offA, eA, wid, lane, lgrp, lidx, sA, &degA);
    seg_sum32(mB, ldm, colB, offB, eB, wid, lane, lgrp, lidx, sB, &degB);
#pragma unroll
    for (int k = 0; k < 4; k++) {
        sA[k] += __shfl_xor(sA[k], 8); sA[k] += __shfl_xor(sA[k], 16); sA[k] += __shfl_xor(sA[k], 32);
        sB[k] += __shfl_xor(sB[k], 8); sB[k] += __shfl_xor(sB[k], 16); sB[k] += __shfl_xor(sB[k], 32);
    }
    if (lane < 8) {
        float ia = 1.f / (float)max(degA, 1), ib = 1.f / (float)max(degB, 1);
        float4 v;
        v.x = sA[0] * ia + sB[0] * ib + bias[lidx * 4 + 0];
        v.y = sA[1] * ia + sB[1] * ib + bias[lidx * 4 + 1];
        v.z = sA[2] * ia + sB[2] * ib + bias[lidx * 4 + 2];
        v.w = sA[3] * ia + sB[3] * ib + bias[lidx * 4 + 3];
        *(float4*)(out + (size_t)wid * 32 + lidx * 4) = v;
    }
}

// ---------------- launcher ----------------
extern "C" void kernel_launch(void* const* d_in, const int* in_sizes, int n_in,
                              void* d_out, int out_size, void* d_ws, size_t ws_size,
                              hipStream_t stream)
{
    const float* xd = (const float*)d_in[0];
    const float* xg = (const float*)d_in[1];
    const int* dd_src = (const int*)d_in[2];  const int* dd_dst = (const int*)d_in[3];
    const int* dg_src = (const int*)d_in[4];  const int* dg_dst = (const int*)d_in[5];
    const int* gd_src = (const int*)d_in[6];  const int* gd_dst = (const int*)d_in[7];
    const int* gg_src = (const int*)d_in[8];  const int* gg_dst = (const int*)d_in[9];
    const float* W1dd = (const float*)d_in[10];
    const float* W1dg = (const float*)d_in[11];
    const float* W1gd = (const float*)d_in[12];
    const float* W1gg = (const float*)d_in[13];
    const float* b1d  = (const float*)d_in[14];
    const float* b1g  = (const float*)d_in[15];
    const float* W2dd = (const float*)d_in[16];
    const float* W2dg = (const float*)d_in[17];
    const float* W2gd = (const float*)d_in[18];
    const float* W2gg = (const float*)d_in[19];
    const float* b2d  = (const float*)d_in[20];
    const float* b2g  = (const float*)d_in[21];
    float* out = (float*)d_out;

    // workspace layout
    int* gcur     = (int*)d_ws;                    // 512
    int* base_rel = gcur + 512;                    // 512
    int* off      = base_rel + 512;                // 4*(N_NODE+1)
    int* edges    = off + 4 * (N_NODE + 1);        // 4*NEDGE
    bf16* xdb     = (bf16*)(edges + 4 * NEDGE);    // 50000*128 bf16
    bf16* xgb     = xdb + (size_t)N_NODE * 128;
    bf16* md1     = xgb + (size_t)N_NODE * 128;    // 50000*128 bf16 (12.8 MB)
    bf16* mg1     = md1 + (size_t)N_NODE * 128;
    bf16* hd      = mg1 + (size_t)N_NODE * 128;    // 50000*64 bf16
    bf16* hg      = hd + (size_t)N_NODE * 64;
    bf16* md2     = md1;
    bf16* mg2     = mg1;
    unsigned* gpart = (unsigned*)md1;              // 512*CAPB uints (12.6 MB), dead before GEMM1

    // ---- CSR build ----
    hipMemsetAsync(gcur, 0, 512 * sizeof(int), stream);
    k_part<<<4 * NBLK1, 256, 0, stream>>>(
        dd_dst, dd_src, gd_dst, gd_src, dg_dst, dg_src, gg_dst, gg_src, gcur, gpart);
    k_base<<<1, 512, 0, stream>>>(gcur, base_rel);
    k_csr<<<512, 256, 0, stream>>>(gpart, gcur, base_rel, off, edges);

    // ---- cast inputs to bf16 ----
    k_cast<<<(N_NODE * 128 / 4 + 255) / 256, 256, 0, stream>>>(
        xd, xg, xdb, xgb, N_NODE * 128 / 4);

    const int* off_dd = off + 0 * (N_NODE + 1);
    const int* off_gd = off + 1 * (N_NODE + 1);
    const int* off_dg = off + 2 * (N_NODE + 1);
    const int* off_gg = off + 3 * (N_NODE + 1);
    const int* e_dd = edges + 0 * NEDGE;
    const int* e_gd = edges + 1 * NEDGE;
    const int* e_dg = edges + 2 * NEDGE;
    const int* e_gg = edges + 3 * NEDGE;

    int gemm_grid = (N_NODE + 63) / 64;

    // ---- layer 1 ----
    k_gemm_mfma<128, 128><<<gemm_grid, 256, 0, stream>>>(xdb, W1dd, W1dg, md1, N_NODE);
    k_gemm_mfma<128, 128><<<gemm_grid, 256, 0, stream>>>(xgb, W1gd, W1gg, mg1, N_NODE);
    k_gather64<<<(N_NODE * 64) / 256, 256, 0, stream>>>(
        md1, 0, mg1, 0, off_dd, e_dd, off_gd, e_gd, b1d, hd, 128, 1);
    k_gather64<<<(N_NODE * 64) / 256, 256, 0, stream>>>(
        md1, 64, mg1, 64, off_dg, e_dg, off_gg, e_gg, b1g, hg, 128, 1);

    // ---- layer 2 ----
    k_gemm_mfma<64, 64><<<gemm_grid, 256, 0, stream>>>(hd, W2dd, W2dg, md2, N_NODE);
    k_gemm_mfma<64, 64><<<gemm_grid, 256, 0, stream>>>(hg, W2gd, W2gg, mg2, N_NODE);
    k_gather32<<<(N_NODE * 64) / 256, 256, 0, stream>>>(
        md2, 0, mg2, 0, off_dd, e_dd, off_gd, e_gd, b2d, out, 64);
    k_gather32<<<(N_NODE * 64) / 256, 256, 0, stream>>>(
        md2, 32, mg2, 32, off_dg, e_dg, off_gg, e_gg, b2g, out + (size_t)N_NODE * 32, 64);
}

// Round 7
// 357.592 us; speedup vs baseline: 2.2962x; 1.1135x over previous
//
#include <hip/hip_runtime.h>
#include <hip/hip_bf16.h>

#define N_NODE 50000
#define NEDGE  600000
#define NRANGE 128
#define RSZ    391       // ceil(N_NODE / NRANGE); 128*391 = 50048 >= 50000
#define CAPB   6144      // slot capacity per (rel,range): mean 4688 + ~21 sigma
#define CHUNK  4096
#define NBLK1  147       // ceil(NEDGE / CHUNK)

typedef __hip_bfloat16 bf16;
struct __attribute__((aligned(8))) bh4 { bf16 a, b, c, d; };
typedef __attribute__((ext_vector_type(8))) short short8;
typedef __attribute__((ext_vector_type(4))) float floatx4;

__device__ __forceinline__ short f2s(float f) {
    bf16 t = __float2bfloat16(f);
    return *(short*)&t;
}

// rel 0 = dd (dst=drug), 1 = gd (dst=drug), 2 = dg (dst=gene), 3 = gg (dst=gene)
// key packing: (bucket:7 << 25) | (dst_local:9 << 16) | (src:16)

// ---------- stage A: partition edges into fixed-capacity (rel,range) slots ----------
__global__ __launch_bounds__(256) void k_part(
    const int* __restrict__ d0, const int* __restrict__ s0,
    const int* __restrict__ d1, const int* __restrict__ s1,
    const int* __restrict__ d2, const int* __restrict__ s2,
    const int* __restrict__ d3, const int* __restrict__ s3,
    int* __restrict__ gcur, unsigned* __restrict__ gpart)
{
    __shared__ int hcur[NRANGE];
    __shared__ int delta[NRANGE];
    __shared__ int sc[256];
    __shared__ unsigned buf[CHUNK];
    int bid = blockIdx.x;
    int rel = bid / NBLK1;
    int c   = bid - rel * NBLK1;
    int tid = threadIdx.x;
    const int* dp = rel == 0 ? d0 : rel == 1 ? d1 : rel == 2 ? d2 : d3;
    const int* sp = rel == 0 ? s0 : rel == 1 ? s1 : rel == 2 ? s2 : s3;
    int e0 = c * CHUNK;
    int e1 = min(e0 + CHUNK, NEDGE);
    int cnt_chunk = e1 - e0;

    if (tid < NRANGE) hcur[tid] = 0;
    __syncthreads();
    for (int e = e0 + tid; e < e1; e += 256)
        atomicAdd(&hcur[dp[e] / RSZ], 1);
    __syncthreads();
    int v = (tid < NRANGE) ? hcur[tid] : 0;
    sc[tid] = v;
    __syncthreads();
    for (int d = 1; d < NRANGE; d <<= 1) {
        int t = (tid >= d && tid < NRANGE) ? sc[tid - d] : 0;
        __syncthreads();
        sc[tid] += t;
        __syncthreads();
    }
    if (tid < NRANGE) {
        int start = sc[tid] - v;
        int bg    = rel * NRANGE + tid;
        int resv  = atomicAdd(&gcur[bg], v);
        delta[tid] = bg * CAPB + resv - start;
        hcur[tid]  = start;
    }
    __syncthreads();
    for (int e = e0 + tid; e < e1; e += 256) {
        int d = dp[e];
        int b = d / RSZ;
        int p = atomicAdd(&hcur[b], 1);
        buf[p] = ((unsigned)b << 25) | ((unsigned)(d - b * RSZ) << 16) | (unsigned)sp[e];
    }
    __syncthreads();
    for (int i = tid; i < cnt_chunk; i += 256) {
        unsigned key = buf[i];
        gpart[delta[key >> 25] + i] = key;
    }
}

// ---------- stage B: per-rel exclusive scan of 512 bucket counts ----------
__global__ __launch_bounds__(512) void k_base(
    const int* __restrict__ gcur, int* __restrict__ base_rel)
{
    __shared__ int sc[512];
    int t = threadIdx.x;
    int v = gcur[t];
    sc[t] = v;
    __syncthreads();
    int loc = t & (NRANGE - 1);
    for (int d = 1; d < NRANGE; d <<= 1) {
        int x = (loc >= d) ? sc[t - d] : 0;
        __syncthreads();
        sc[t] += x;
        __syncthreads();
    }
    base_rel[t] = sc[t] - v;
}

// ---------- stage C: per (rel,range) block -> final CSR (off + edges) ----------
__global__ __launch_bounds__(256) void k_csr(
    const unsigned* __restrict__ gpart, const int* __restrict__ gcnt,
    const int* __restrict__ base_rel, int* __restrict__ off, int* __restrict__ edges)
{
    __shared__ int cur[RSZ];
    __shared__ unsigned short stg[CAPB];
    __shared__ int sc[256];
    int bid = blockIdx.x;
    int rel = bid >> 7, r = bid & (NRANGE - 1);
    int tid = threadIdx.x;
    int range0 = r * RSZ;
    int RS = min(RSZ, N_NODE - range0);
    if (RS < 0) RS = 0;
    int count = gcnt[bid];
    int base  = base_rel[bid];
    size_t slot0 = (size_t)bid * CAPB;

    for (int i = tid; i < RSZ; i += 256) cur[i] = 0;
    __syncthreads();
    for (int i = tid; i < count; i += 256)
        atomicAdd(&cur[(gpart[slot0 + i] >> 16) & 0x1FF], 1);
    __syncthreads();
    int vloc[2]; int run = 0;
#pragma unroll
    for (int j = 0; j < 2; j++) {
        int idx = tid * 2 + j;
        int x = (idx < RSZ) ? cur[idx] : 0;
        vloc[j] = x; run += x;
    }
    sc[tid] = run;
    __syncthreads();
    for (int d = 1; d < 256; d <<= 1) {
        int t = (tid >= d) ? sc[tid - d] : 0;
        __syncthreads();
        sc[tid] += t;
        __syncthreads();
    }
    int excl = sc[tid] - run;
    run = excl;
#pragma unroll
    for (int j = 0; j < 2; j++) {
        int idx = tid * 2 + j;
        if (idx < RSZ) { int x = vloc[j]; cur[idx] = run; run += x; }
    }
    __syncthreads();
    for (int i = tid; i < RS; i += 256)
        off[rel * (N_NODE + 1) + range0 + i] = base + cur[i];
    if (r == NRANGE - 1 && tid == 0) off[rel * (N_NODE + 1) + N_NODE] = NEDGE;
    __syncthreads();
    for (int i = tid; i < count; i += 256) {
        unsigned key = gpart[slot0 + i];
        int p = atomicAdd(&cur[(key >> 16) & 0x1FF], 1);
        stg[p] = (unsigned short)(key & 0xFFFFu);
    }
    __syncthreads();
    for (int i = tid; i < count; i += 256)
        edges[rel * NEDGE + base + i] = (int)stg[i];
}

// ---------- MFMA dual-weight GEMM pair: out(bf16) = X @ [Wa | Wb], 2 problems ----------
template <int K, int NOUT, bool AFP32>
__global__ __launch_bounds__(256) void k_gemm_pair(
    const void* __restrict__ X0, const void* __restrict__ X1,
    const float* __restrict__ Wa0, const float* __restrict__ Wb0,
    const float* __restrict__ Wa1, const float* __restrict__ Wb1,
    bf16* __restrict__ out0, bf16* __restrict__ out1, int M)
{
    constexpr int NB  = NOUT / 16;
    constexpr int KC  = K / 32;
    constexpr int NH  = NOUT / 2;
    constexpr int NBL = (NB == 8) ? 3 : 2;
    __shared__ short Wl[KC * NB * 512];

    int sel = blockIdx.y;
    const void*  X  = sel ? X1 : X0;
    const float* Wa = sel ? Wa1 : Wa0;
    const float* Wb = sel ? Wb1 : Wb0;
    bf16*        out = sel ? out1 : out0;

    int tid = threadIdx.x;
    for (int i = tid; i < KC * NB * 512; i += 256) {
        int j  = i & 7;
        int n  = (i >> 3) & 15;
        int q  = (i >> 7) & 3;
        int nb = (i >> 9) & (NB - 1);
        int kc = i >> (9 + NBL);
        int k  = kc * 32 + q * 8 + j;
        int c  = nb * 16 + n;
        float w = (c < NH) ? Wa[k * NH + c] : Wb[k * NH + (c - NH)];
        Wl[i] = f2s(w);
    }
    __syncthreads();

    int lane = tid & 63, wv = tid >> 6;
    int q = lane >> 4, lidx = lane & 15;
    int row0 = blockIdx.x * 64 + wv * 16;
    int rowA = min(row0 + lidx, M - 1);

    floatx4 acc[NB];
#pragma unroll
    for (int nb = 0; nb < NB; nb++) acc[nb] = (floatx4){0.f, 0.f, 0.f, 0.f};

#pragma unroll
    for (int kc = 0; kc < KC; kc++) {
        short8 a;
        if constexpr (AFP32) {
            const float* Xf = (const float*)X + (size_t)rowA * K + kc * 32 + q * 8;
            float4 f0 = *(const float4*)Xf;
            float4 f1 = *(const float4*)(Xf + 4);
            a[0] = f2s(f0.x); a[1] = f2s(f0.y); a[2] = f2s(f0.z); a[3] = f2s(f0.w);
            a[4] = f2s(f1.x); a[5] = f2s(f1.y); a[6] = f2s(f1.z); a[7] = f2s(f1.w);
        } else {
            a = *(const short8*)((const short*)X + (size_t)rowA * K + kc * 32 + q * 8);
        }
#pragma unroll
        for (int nb = 0; nb < NB; nb++) {
            short8 b = *(const short8*)&Wl[((kc * NB + nb) * 64 + lane) * 8];
            acc[nb] = __builtin_amdgcn_mfma_f32_16x16x32_bf16(a, b, acc[nb], 0, 0, 0);
        }
    }
#pragma unroll
    for (int nb = 0; nb < NB; nb++) {
#pragma unroll
        for (int r = 0; r < 4; r++) {
            int row = row0 + q * 4 + r;
            if (row < M)
                out[(size_t)row * NOUT + nb * 16 + lidx] = __float2bfloat16(acc[nb][r]);
        }
    }
}

// ---------- seg-sum, 64 feat: 16 lanes/edge, 2x unrolled (8 edges in flight) ----------
__device__ __forceinline__ void seg_sum64u(
    const unsigned short* __restrict__ mb, int ldm,
    int beg, int end, const int* __restrict__ edges,
    int lane, int lgrp, const unsigned short* base, float s[4])
{
    for (int e = beg; e < end; e += 64) {
        int nb = min(64, end - e);
        int eidx = (lane < nb) ? edges[e + lane] : 0;
        int full = nb & ~7;
        int j = 0;
        for (; j < full; j += 8) {
            int sa = __shfl(eidx, j + lgrp);
            int sb = __shfl(eidx, j + 4 + lgrp);
            uint2 wa = *(const uint2*)(base + (size_t)sa * ldm);
            uint2 wb = *(const uint2*)(base + (size_t)sb * ldm);
            s[0] += __uint_as_float(wa.x << 16);
            s[1] += __uint_as_float(wa.x & 0xFFFF0000u);
            s[2] += __uint_as_float(wa.y << 16);
            s[3] += __uint_as_float(wa.y & 0xFFFF0000u);
            s[0] += __uint_as_float(wb.x << 16);
            s[1] += __uint_as_float(wb.x & 0xFFFF0000u);
            s[2] += __uint_as_float(wb.y << 16);
            s[3] += __uint_as_float(wb.y & 0xFFFF0000u);
        }
        for (; j < nb; j += 4) {
            int sa = __shfl(eidx, j + lgrp);
            float vm = (j + lgrp < nb) ? 1.f : 0.f;
            uint2 w = *(const uint2*)(base + (size_t)sa * ldm);
            s[0] += vm * __uint_as_float(w.x << 16);
            s[1] += vm * __uint_as_float(w.x & 0xFFFF0000u);
            s[2] += vm * __uint_as_float(w.y << 16);
            s[3] += vm * __uint_as_float(w.y & 0xFFFF0000u);
        }
    }
}

// ---------- fused layer-1 gather: half 0 -> hd (cols 0), half 1 -> hg (cols 64) ----------
__global__ __launch_bounds__(256) void k_gather64x2(
    const bf16* __restrict__ m1, const bf16* __restrict__ m2,
    const int* __restrict__ offA0, const int* __restrict__ eA0,
    const int* __restrict__ offB0, const int* __restrict__ eB0,
    const float* __restrict__ bias0, bf16* __restrict__ out0,
    const int* __restrict__ offA1, const int* __restrict__ eA1,
    const int* __restrict__ offB1, const int* __restrict__ eB1,
    const float* __restrict__ bias1, bf16* __restrict__ out1)
{
    int gw   = (blockIdx.x * 256 + threadIdx.x) >> 6;
    int lane = threadIdx.x & 63;
    int half = (gw >= N_NODE);
    int wid  = gw - (half ? N_NODE : 0);
    const int* offA = half ? offA1 : offA0;
    const int* eA   = half ? eA1   : eA0;
    const int* offB = half ? offB1 : offB0;
    const int* eB   = half ? eB1   : eB0;
    const float* bias = half ? bias1 : bias0;
    bf16* out = half ? out1 : out0;
    int col = half ? 64 : 0;

    int lgrp = lane >> 4, lidx = lane & 15;
    const unsigned short* mb1 = (const unsigned short*)m1;
    const unsigned short* mb2 = (const unsigned short*)m2;
    const unsigned short* base1 = mb1 + col + lidx * 4;
    const unsigned short* base2 = mb2 + col + lidx * 4;

    int begA = offA[wid], endA = offA[wid + 1];
    int begB = offB[wid], endB = offB[wid + 1];
    float sA[4] = {0.f, 0.f, 0.f, 0.f}, sB[4] = {0.f, 0.f, 0.f, 0.f};
    seg_sum64u(mb1, 128, begA, endA, eA, lane, lgrp, base1, sA);
    seg_sum64u(mb2, 128, begB, endB, eB, lane, lgrp, base2, sB);
#pragma unroll
    for (int k = 0; k < 4; k++) {
        sA[k] += __shfl_xor(sA[k], 16); sA[k] += __shfl_xor(sA[k], 32);
        sB[k] += __shfl_xor(sB[k], 16); sB[k] += __shfl_xor(sB[k], 32);
    }
    if (lane < 16) {
        float ia = 1.f / (float)max(endA - begA, 1);
        float ib = 1.f / (float)max(endB - begB, 1);
        float h0 = fmaxf(sA[0] * ia + sB[0] * ib + bias[lidx * 4 + 0], 0.f);
        float h1 = fmaxf(sA[1] * ia + sB[1] * ib + bias[lidx * 4 + 1], 0.f);
        float h2 = fmaxf(sA[2] * ia + sB[2] * ib + bias[lidx * 4 + 2], 0.f);
        float h3 = fmaxf(sA[3] * ia + sB[3] * ib + bias[lidx * 4 + 3], 0.f);
        bh4 v = { __float2bfloat16(h0), __float2bfloat16(h1),
                  __float2bfloat16(h2), __float2bfloat16(h3) };
        *(bh4*)(out + (size_t)wid * 64 + lidx * 4) = v;
    }
}

// ---------- seg-sum, 32 feat: 8 lanes/edge, 2x unrolled (16 edges in flight) ----------
__device__ __forceinline__ void seg_sum32u(
    int beg, int end, const int* __restrict__ edges,
    int lane, int lgrp, int ldm, const unsigned short* base, float s[4])
{
    for (int e = beg; e < end; e += 64) {
        int nb = min(64, end - e);
        int eidx = (lane < nb) ? edges[e + lane] : 0;
        int full = nb & ~15;
        int j = 0;
        for (; j < full; j += 16) {
            int sa = __shfl(eidx, j + lgrp);
            int sb = __shfl(eidx, j + 8 + lgrp);
            uint2 wa = *(const uint2*)(base + (size_t)sa * ldm);
            uint2 wb = *(const uint2*)(base + (size_t)sb * ldm);
            s[0] += __uint_as_float(wa.x << 16);
            s[1] += __uint_as_float(wa.x & 0xFFFF0000u);
            s[2] += __uint_as_float(wa.y << 16);
            s[3] += __uint_as_float(wa.y & 0xFFFF0000u);
            s[0] += __uint_as_float(wb.x << 16);
            s[1] += __uint_as_float(wb.x & 0xFFFF0000u);
            s[2] += __uint_as_float(wb.y << 16);
            s[3] += __uint_as_float(wb.y & 0xFFFF0000u);
        }
        for (; j < nb; j += 8) {
            int sa = __shfl(eidx, j + lgrp);
            float vm = (j + lgrp < nb) ? 1.f : 0.f;
            uint2 w = *(const uint2*)(base + (size_t)sa * ldm);
            s[0] += vm * __uint_as_float(w.x << 16);
            s[1] += vm * __uint_as_float(w.x & 0xFFFF0000u);
            s[2] += vm * __uint_as_float(w.y << 16);
            s[3] += vm * __uint_as_float(w.y & 0xFFFF0000u);
        }
    }
}

// ---------- fused layer-2 gather: half 0 -> out[0:N] (cols 0), half 1 -> out[N:] (cols 32) ----------
__global__ __launch_bounds__(256) void k_gather32x2(
    const bf16* __restrict__ m1, const bf16* __restrict__ m2,
    const int* __restrict__ offA0, const int* __restrict__ eA0,
    const int* __restrict__ offB0, const int* __restrict__ eB0,
    const float* __restrict__ bias0, float* __restrict__ out0,
    const int* __restrict__ offA1, const int* __restrict__ eA1,
    const int* __restrict__ offB1, const int* __restrict__ eB1,
    const float* __restrict__ bias1, float* __restrict__ out1)
{
    int gw   = (blockIdx.x * 256 + threadIdx.x) >> 6;
    int lane = threadIdx.x & 63;
    int half = (gw >= N_NODE);
    int wid  = gw - (half ? N_NODE : 0);
    const int* offA = half ? offA1 : offA0;
    const int* eA   = half ? eA1   : eA0;
    const int* offB = half ? offB1 : offB0;
    const int* eB   = half ? eB1   : eB0;
    const float* bias = half ? bias1 : bias0;
    float* out = half ? out1 : out0;
    int col = half ? 32 : 0;

    int lgrp = lane >> 3, lidx = lane & 7;
    const unsigned short* base1 = (const unsigned short*)m1 + col + lidx * 4;
    const unsigned short* base2 = (const unsigned short*)m2 + col + lidx * 4;

    int begA = offA[wid], endA = offA[wid + 1];
    int begB = offB[wid], endB = offB[wid + 1];
    float sA[4] = {0.f, 0.f, 0.f, 0.f}, sB[4] = {0.f, 0.f, 0.f, 0.f};
    seg_sum32u(begA, endA, eA, lane, lgrp, 64, base1, sA);
    seg_sum32u(begB, endB, eB, lane, lgrp, 64, base2, sB);
#pragma unroll
    for (int k = 0; k < 4; k++) {
        sA[k] += __shfl_xor(sA[k], 8); sA[k] += __shfl_xor(sA[k], 16); sA[k] += __shfl_xor(sA[k], 32);
        sB[k] += __shfl_xor(sB[k], 8); sB[k] += __shfl_xor(sB[k], 16); sB[k] += __shfl_xor(sB[k], 32);
    }
    if (lane < 8) {
        float ia = 1.f / (float)max(endA - begA, 1);
        float ib = 1.f / (float)max(endB - begB, 1);
        float4 v;
        v.x = sA[0] * ia + sB[0] * ib + bias[lidx * 4 + 0];
        v.y = sA[1] * ia + sB[1] * ib + bias[lidx * 4 + 1];
        v.z = sA[2] * ia + sB[2] * ib + bias[lidx * 4 + 2];
        v.w = sA[3] * ia + sB[3] * ib + bias[lidx * 4 + 3];
        *(float4*)(out + (size_t)wid * 32 + lidx * 4) = v;
    }
}

// ---------------- launcher ----------------
extern "C" void kernel_launch(void* const* d_in, const int* in_sizes, int n_in,
                              void* d_out, int out_size, void* d_ws, size_t ws_size,
                              hipStream_t stream)
{
    const float* xd = (const float*)d_in[0];
    const float* xg = (const float*)d_in[1];
    const int* dd_src = (const int*)d_in[2];  const int* dd_dst = (const int*)d_in[3];
    const int* dg_src = (const int*)d_in[4];  const int* dg_dst = (const int*)d_in[5];
    const int* gd_src = (const int*)d_in[6];  const int* gd_dst = (const int*)d_in[7];
    const int* gg_src = (const int*)d_in[8];  const int* gg_dst = (const int*)d_in[9];
    const float* W1dd = (const float*)d_in[10];
    const float* W1dg = (const float*)d_in[11];
    const float* W1gd = (const float*)d_in[12];
    const float* W1gg = (const float*)d_in[13];
    const float* b1d  = (const float*)d_in[14];
    const float* b1g  = (const float*)d_in[15];
    const float* W2dd = (const float*)d_in[16];
    const float* W2dg = (const float*)d_in[17];
    const float* W2gd = (const float*)d_in[18];
    const float* W2gg = (const float*)d_in[19];
    const float* b2d  = (const float*)d_in[20];
    const float* b2g  = (const float*)d_in[21];
    float* out = (float*)d_out;

    // workspace layout
    int* gcur     = (int*)d_ws;                    // 512
    int* base_rel = gcur + 512;                    // 512
    int* off      = base_rel + 512;                // 4*(N_NODE+1)
    int* edges    = off + 4 * (N_NODE + 1);        // 4*NEDGE
    bf16* md1     = (bf16*)(edges + 4 * NEDGE);    // 50000*128 bf16 (12.8 MB)
    bf16* mg1     = md1 + (size_t)N_NODE * 128;
    bf16* hd      = mg1 + (size_t)N_NODE * 128;    // 50000*64 bf16
    bf16* hg      = hd + (size_t)N_NODE * 64;
    bf16* md2     = md1;
    bf16* mg2     = mg1;
    unsigned* gpart = (unsigned*)md1;              // 512*CAPB uints (12.6 MB), dead before GEMM1

    // ---- CSR build ----
    hipMemsetAsync(gcur, 0, 512 * sizeof(int), stream);
    k_part<<<4 * NBLK1, 256, 0, stream>>>(
        dd_dst, dd_src, gd_dst, gd_src, dg_dst, dg_src, gg_dst, gg_src, gcur, gpart);
    k_base<<<1, 512, 0, stream>>>(gcur, base_rel);
    k_csr<<<512, 256, 0, stream>>>(gpart, gcur, base_rel, off, edges);

    const int* off_dd = off + 0 * (N_NODE + 1);
    const int* off_gd = off + 1 * (N_NODE + 1);
    const int* off_dg = off + 2 * (N_NODE + 1);
    const int* off_gg = off + 3 * (N_NODE + 1);
    const int* e_dd = edges + 0 * NEDGE;
    const int* e_gd = edges + 1 * NEDGE;
    const int* e_dg = edges + 2 * NEDGE;
    const int* e_gg = edges + 3 * NEDGE;

    dim3 gemm_grid((N_NODE + 63) / 64, 2);
    int gather_grid = 2 * N_NODE / 4;   // 2*N waves, 4 waves/block

    // ---- layer 1 ----
    k_gemm_pair<128, 128, true><<<gemm_grid, 256, 0, stream>>>(
        xd, xg, W1dd, W1dg, W1gd, W1gg, md1, mg1, N_NODE);
    k_gather64x2<<<gather_grid, 256, 0, stream>>>(
        md1, mg1,
        off_dd, e_dd, off_gd, e_gd, b1d, hd,
        off_dg, e_dg, off_gg, e_gg, b1g, hg);

    // ---- layer 2 ----
    k_gemm_pair<64, 64, false><<<gemm_grid, 256, 0, stream>>>(
        hd, hg, W2dd, W2dg, W2gd, W2gg, md2, mg2, N_NODE);
    k_gather32x2<<<gather_grid, 256, 0, stream>>>(
        md2, mg2,
        off_dd, e_dd, off_gd, e_gd, b2d, out,
        off_dg, e_dg, off_gg, e_gg, b2g, out + (size_t)N_NODE * 32);
}